// Round 5
// baseline (999.776 us; speedup 1.0000x reference)
//
#include <hip/hip_runtime.h>
#include <stdint.h>

#define NB    4
#define TQ    256
#define TS    257
#define TD    65
#define NPIX  16640        /* TQ*TD */
#define NPADQ 264          /* padded s per q */
#define NPAD  67584        /* 256*264 */
#define COUT  512
#define HID   256

typedef __attribute__((ext_vector_type(8))) short bf16x8;
typedef __attribute__((ext_vector_type(4))) float f32x4;

// ---------------- bf16 helpers ----------------
__device__ __forceinline__ float bf2f(unsigned short u) {
    union { unsigned int i; float f; } v; v.i = ((unsigned int)u) << 16; return v.f;
}
__device__ __forceinline__ unsigned short f2bf(float x) {
    union { float f; unsigned int i; } v; v.f = x;
    unsigned int r = v.i + 0x7fffu + ((v.i >> 16) & 1u);
    return (unsigned short)(r >> 16);
}

__device__ __forceinline__ float2 gn_params(const float* st, int bg, float invcnt) {
    float mu  = st[bg * 2] * invcnt;
    float var = st[bg * 2 + 1] * invcnt - mu * mu;
    float2 r; r.x = mu; r.y = rsqrtf(var + 1e-5f); return r;
}

// ---------------- weight cast fp32 -> bf16 ----------------
__global__ void wprep_kernel(const float* __restrict__ wq, const float* __restrict__ wsc,
                             const float* __restrict__ wagg, unsigned short* __restrict__ wb) {
    int i = blockIdx.x * 256 + threadIdx.x;   // grid 1152 -> 294912
    float v;
    if (i < 98304) v = wq[i];
    else if (i < 163840) v = wsc[i - 98304];
    else v = wagg[i - 163840];
    wb[i] = f2bf(v);
}

// ---------------- mask: additive bias table [b][272] (0 or -1e9) ----------------
__global__ void mask_kernel(const int* __restrict__ sm, float* __restrict__ bias) {
    int b = blockIdx.x; int t = threadIdx.x;   // 320 threads
    if (t >= 272) return;
    float v;
    if (t == 0) v = 0.0f;
    else if (t <= 256) {
        int s = t - 1; int i = s >> 4, j = s & 15;
        v = (sm[(size_t)b * 65536 + i * 17 * 256 + j * 17] != 0) ? 0.0f : -1e9f;
    } else v = -1e9f;
    bias[b * 272 + t] = v;
}

// ---------------- fused transpose + pool ----------------
__global__ __launch_bounds__(256) void tpool_kernel(
    const float* __restrict__ corr,
    unsigned short* __restrict__ corrT,    // [b][NPAD][128]
    unsigned short* __restrict__ corrpT)   // [b][NPIX][128]
{
    int q = blockIdx.x, ch = blockIdx.y, b = blockIdx.z;
    int t = threadIdx.x;
    __shared__ unsigned short sT[264 * 66];

    {
        int laneT = t & 63; int crow = t >> 6;
        for (int c = crow; c < 64; c += 4) {
            const float* src = corr + (((size_t)b * 128 + ch * 64 + c) * 256 + q) * 257;
            for (int s = laneT; s < 257; s += 64) sT[s * 66 + c] = f2bf(src[s]);
        }
    }
    for (int idx = t; idx < 7 * 66; idx += 256) {
        int s = 257 + idx / 66, c = idx % 66;
        sT[s * 66 + c] = 0;
    }
    __syncthreads();

    {
        unsigned int* dst = (unsigned int*)corrT;
        size_t base = (size_t)b * (NPAD * 64) + (size_t)q * (264 * 64) + ch * 32;
        for (int idx = t; idx < 264 * 32; idx += 256) {
            int s = idx >> 5, cu = idx & 31;
            unsigned int v = (unsigned int)sT[s * 66 + 2 * cu] |
                             ((unsigned int)sT[s * 66 + 2 * cu + 1] << 16);
            dst[base + (size_t)s * 64 + cu] = v;
        }
    }
    {
        unsigned int* dst = (unsigned int*)corrpT;
        size_t base = (size_t)b * (NPIX * 64) + (size_t)q * (65 * 64) + ch * 32;
        for (int idx = t; idx < 65 * 32; idx += 256) {
            int d = idx >> 5, cu = idx & 31;
            float x0, x1;
            if (d == 0) {
                x0 = bf2f(sT[0 * 66 + 2 * cu]); x1 = bf2f(sT[0 * 66 + 2 * cu + 1]);
            } else {
                int dd = d - 1; int i = dd >> 3, j = dd & 7;
                int s = 1 + i * 32 + j * 2;
                int c0 = 2 * cu, c1 = 2 * cu + 1;
                x0 = 0.25f * (bf2f(sT[s*66+c0]) + bf2f(sT[(s+1)*66+c0]) +
                              bf2f(sT[(s+16)*66+c0]) + bf2f(sT[(s+17)*66+c0]));
                x1 = 0.25f * (bf2f(sT[s*66+c1]) + bf2f(sT[(s+1)*66+c1]) +
                              bf2f(sT[(s+16)*66+c1]) + bf2f(sT[(s+17)*66+c1]));
            }
            unsigned int v = (unsigned int)f2bf(x0) | ((unsigned int)f2bf(x1) << 16);
            dst[base + (size_t)d * 64 + cu] = v;
        }
    }
}

// ---------------- unified MFMA GEMM (modes 0,2,3 used) ----------------
template<int MODE, int KT>
__global__ __launch_bounds__(256) void mgemm_kernel(
    const unsigned short* __restrict__ X,
    const unsigned short* __restrict__ Wb,
    int Nn,
    float* __restrict__ Yf,
    unsigned short* __restrict__ Y16,
    const float* __restrict__ bias,
    const float* __restrict__ st, const float* __restrict__ gw, const float* __restrict__ gb,
    float invcnt)
{
    int b  = blockIdx.z;
    int n0 = blockIdx.x * 128;
    int m0 = blockIdx.y * 128;
    int t = threadIdx.x;
    int w = t >> 6, lane = t & 63;
    int lm = lane & 15, lg = lane >> 4;
    int wn = (w & 1) * 64, wm = (w >> 1) * 64;

    __shared__ __align__(16) unsigned short sX[16384];
    __shared__ __align__(16) unsigned short sW[16384];

    f32x4 acc[4][4];
    #pragma unroll
    for (int i = 0; i < 4; i++)
        #pragma unroll
        for (int j = 0; j < 4; j++) { acc[i][j][0]=0.f; acc[i][j][1]=0.f; acc[i][j][2]=0.f; acc[i][j][3]=0.f; }

    for (int kc = 0; kc < KT / 128; kc++) {
        for (int i = t; i < 2048; i += 256) {
            int r_ = i >> 4, kq = i & 15;
            uint4 xv = *(const uint4*)&X[((size_t)b * Nn + n0 + r_) * KT + kc * 128 + (kq << 3)];
            if (MODE == 3) {
                union { uint4 v; unsigned short us[8]; } u; u.v = xv;
                int c0 = kc * 128 + (kq << 3);
                float2 p = gn_params(st, b * 4 + (c0 >> 6), invcnt);
                #pragma unroll
                for (int jj = 0; jj < 8; jj++) {
                    int cc = c0 + jj;
                    float v = bf2f(u.us[jj]);
                    v = fmaxf((v - p.x) * p.y * gw[cc] + gb[cc], 0.0f);
                    u.us[jj] = f2bf(v);
                }
                xv = u.v;
            }
            *(uint4*)&sX[r_ * 128 + ((kq ^ (r_ & 15)) << 3)] = xv;
            uint4 wv = *(const uint4*)&Wb[((size_t)(m0 + r_)) * KT + kc * 128 + (kq << 3)];
            *(uint4*)&sW[r_ * 128 + ((kq ^ (r_ & 15)) << 3)] = wv;
        }
        __syncthreads();
        #pragma unroll
        for (int kk = 0; kk < 4; kk++) {
            int kg = (kk << 2) | lg;
            bf16x8 af[4], bw[4];
            #pragma unroll
            for (int ii = 0; ii < 4; ii++)
                af[ii] = *(const bf16x8*)&sX[(wn + ii * 16 + lm) * 128 + ((kg ^ lm) << 3)];
            #pragma unroll
            for (int jj = 0; jj < 4; jj++)
                bw[jj] = *(const bf16x8*)&sW[(wm + jj * 16 + lm) * 128 + ((kg ^ lm) << 3)];
            #pragma unroll
            for (int ii = 0; ii < 4; ii++)
                #pragma unroll
                for (int jj = 0; jj < 4; jj++) {
                    if (MODE == 0)
                        acc[ii][jj] = __builtin_amdgcn_mfma_f32_16x16x32_bf16(bw[jj], af[ii], acc[ii][jj], 0,0,0);
                    else
                        acc[ii][jj] = __builtin_amdgcn_mfma_f32_16x16x32_bf16(af[ii], bw[jj], acc[ii][jj], 0,0,0);
                }
        }
        __syncthreads();
    }

    if (MODE == 0) {
        #pragma unroll
        for (int ii = 0; ii < 4; ii++) {
            int n = n0 + wn + ii * 16 + lm;
            #pragma unroll
            for (int jj = 0; jj < 4; jj++) {
                int mb = m0 + wm + jj * 16 + lg * 4;
                union { unsigned short us[4]; uint2 v; } pk;
                #pragma unroll
                for (int r = 0; r < 4; r++) pk.us[r] = f2bf(acc[ii][jj][r] + bias[mb + r]);
                *(uint2*)&Y16[((size_t)b * NPIX + n) * 256 + mb] = pk.v;
            }
        }
    } else {
        #pragma unroll
        for (int ii = 0; ii < 4; ii++) {
            int nb = n0 + wn + ii * 16 + lg * 4;
            #pragma unroll
            for (int jj = 0; jj < 4; jj++) {
                int m = m0 + wm + jj * 16 + lm;
                *(f32x4*)&Yf[((size_t)b * COUT + m) * NPIX + nb] = acc[ii][jj];
            }
        }
    }
}

// ---------------- fused KV-projection + MFMA attention ----------------
// grid (8, 256, 4); 320 threads = 5 waves. (g,q) REMAPPED from flat id so that all
// 8 g-blocks (and all 4 b's) sharing one corrT q-tile land on the SAME XCD:
//   lin = by*8+bx; xcd = lin&7; idx = lin>>3; q = xcd*32 + (idx&31); g = idx>>5.
// (dispatch round-robins flat id across 8 XCDs; lin&7 is XCD-invariant under z.)
// Phase 1: K[264s][32e], V[32ch][264s] in LDS from corrT tile x W_kv (L1-hot), with
//   next-tile ct prefetch so (L2-hit) load latency hides under 16 MFMAs + LDS writes.
// Phase 2: QK^T, bias, softmax, in-reg P transpose, PV (unchanged from round 2/3).
// LDS: K at [0,17408) = [272 s][32 e]; V at [17408,35840) = [9 kk][32 ch][32 s].
// Swizzle: 16B-slot sl within each 256B macro-row stored at sl ^ (mr&15) (region-relative mr).
__global__ __launch_bounds__(320, 3) void attn_kernel(
    const unsigned short* __restrict__ corrT, // [b][NPAD][128]
    const unsigned short* __restrict__ wkv,   // [512][128] bf16: rows 0..255 Wk, 256..511 Wv
    const float* __restrict__ bkv,            // [512] fp32 bias: K then V
    const unsigned short* __restrict__ qpT,   // [b][NPIX][256]
    const float* __restrict__ bias272,        // [b][272] additive mask bias
    unsigned short* __restrict__ attT)        // [b][NPIX][256]
{
    int lin = blockIdx.y * 8 + blockIdx.x;
    int xcd = lin & 7, idx = lin >> 3;
    int q = (xcd << 5) | (idx & 31);
    int g = idx >> 5;
    int b = blockIdx.z;
    int t = threadIdx.x;
    int w = t >> 6, lane = t & 63;
    int lm = lane & 15, lg = lane >> 4;

    __shared__ __align__(16) unsigned short sbuf[17920];   // 35840 B: K then V
    const int VB = 8704;                                    // V base in shorts

    // Q frag (B operand: lane holds Q[d=16w+lm][e=g*32+lg*8+j]); clamp + zero d>=65
    int d = w * 16 + lm;
    int dc = d < 64 ? d : 64;
    bf16x8 qa = *(const bf16x8*)&qpT[((size_t)b * NPIX + q * 65 + dc) * 256 + g * 32 + lg * 8];
    if (d >= TD) { bf16x8 z = {}; qa = z; }

    // ---- phase 1: in-block K/V projection ----
    bf16x8 wkf[2][4], wvf[2][4];
    #pragma unroll
    for (int et = 0; et < 2; et++)
        #pragma unroll
        for (int ks = 0; ks < 4; ks++) {
            wkf[et][ks] = *(const bf16x8*)&wkv[(size_t)(g * 32 + et * 16 + lm) * 128 + ks * 32 + lg * 8];
            wvf[et][ks] = *(const bf16x8*)&wkv[(size_t)(256 + g * 32 + et * 16 + lm) * 128 + ks * 32 + lg * 8];
        }
    float bk_[2][4], bv_[2];
    #pragma unroll
    for (int et = 0; et < 2; et++) {
        #pragma unroll
        for (int r = 0; r < 4; r++) bk_[et][r] = bkv[g * 32 + et * 16 + lg * 4 + r];
        bv_[et] = bkv[256 + g * 32 + et * 16 + lm];
    }

    const unsigned short* cbase = corrT + ((size_t)b * NPAD + (size_t)q * 264) * 128;
    f32x4 zero4 = {0.f, 0.f, 0.f, 0.f};

    bf16x8 ct[4];
    {
        int srow = w * 16 + lm; if (srow > 263) srow = 263;
        #pragma unroll
        for (int ks = 0; ks < 4; ks++)
            ct[ks] = *(const bf16x8*)&cbase[(size_t)srow * 128 + ks * 32 + lg * 8];
    }
    for (int sti = w; sti < 17; sti += 5) {
        int stn = sti + 5;
        bf16x8 ctn[4];
        if (stn < 17) {                        // prefetch next tile's fragments
            int srow = stn * 16 + lm; if (srow > 263) srow = 263;
            #pragma unroll
            for (int ks = 0; ks < 4; ks++)
                ctn[ks] = *(const bf16x8*)&cbase[(size_t)srow * 128 + ks * 32 + lg * 8];
        }
        f32x4 ak0 = zero4, ak1 = zero4, av0 = zero4, av1 = zero4;
        #pragma unroll
        for (int ks = 0; ks < 4; ks++) {
            ak0 = __builtin_amdgcn_mfma_f32_16x16x32_bf16(wkf[0][ks], ct[ks], ak0, 0, 0, 0);
            ak1 = __builtin_amdgcn_mfma_f32_16x16x32_bf16(wkf[1][ks], ct[ks], ak1, 0, 0, 0);
            av0 = __builtin_amdgcn_mfma_f32_16x16x32_bf16(ct[ks], wvf[0][ks], av0, 0, 0, 0);
            av1 = __builtin_amdgcn_mfma_f32_16x16x32_bf16(ct[ks], wvf[1][ks], av1, 0, 0, 0);
        }
        // K writes: lane holds K[e=et*16+lg*4+r][s=sti*16+lm]
        {
            int s = sti * 16 + lm;
            #pragma unroll
            for (int et = 0; et < 2; et++) {
                unsigned u = (unsigned)(s * 64 + et * 32 + lg * 8);
                unsigned mr = u >> 8, sl = (u >> 4) & 15;
                unsigned us = (u & ~0xF0u) | ((sl ^ (mr & 15)) << 4);
                union { unsigned short e[4]; uint2 v; } pk;
                f32x4 a = et ? ak1 : ak0;
                #pragma unroll
                for (int r = 0; r < 4; r++) pk.e[r] = f2bf(a[r] + bk_[et][r]);
                *(uint2*)((char*)sbuf + us) = pk.v;
            }
        }
        // V writes: lane holds V[ch=et*16+lm][s=sti*16+lg*4+r]
        {
            int s0 = sti * 16 + lg * 4;
            unsigned vb_off = (unsigned)((s0 >> 5) * 2048 + (s0 & 31) * 2);
            #pragma unroll
            for (int et = 0; et < 2; et++) {
                int ch = et * 16 + lm;
                unsigned ov = vb_off + (unsigned)ch * 64u;
                unsigned mr = ov >> 8, sl = (ov >> 4) & 15;
                unsigned ovs = (ov & ~0xF0u) | ((sl ^ (mr & 15)) << 4);
                union { unsigned short e[4]; uint2 v; } pk;
                f32x4 a = et ? av1 : av0;
                #pragma unroll
                for (int r = 0; r < 4; r++) pk.e[r] = f2bf(a[r] + bv_[et]);
                *(uint2*)((char*)sbuf + 17408 + ovs) = pk.v;
            }
        }
        if (stn < 17) {
            #pragma unroll
            for (int ks = 0; ks < 4; ks++) ct[ks] = ctn[ks];
        }
    }
    // zero-fill V window s in [272,288)
    if (t < 128) {
        int ch = t >> 2, j = t & 3;
        unsigned ov = 16384u + (unsigned)ch * 64u + 32u + (unsigned)j * 8u;
        unsigned mr = ov >> 8, sl = (ov >> 4) & 15;
        unsigned ovs = (ov & ~0xF0u) | ((sl ^ (mr & 15)) << 4);
        uint2 z2; z2.x = 0u; z2.y = 0u;
        *(uint2*)((char*)sbuf + 17408 + ovs) = z2;
    }
    __syncthreads();

    // ---- phase 2: QK^T from LDS: c[tt] holds S^T[s=16tt+4lg+r][d=lm] ----
    f32x4 c[17];
    int sl0 = ((lm & 3) << 2) | lg;
    #pragma unroll
    for (int tt = 0; tt < 17; tt++) {
        int mr = tt * 4 + (lm >> 2);
        bf16x8 kf = *(const bf16x8*)&sbuf[mr * 128 + ((sl0 ^ (mr & 15)) << 3)];
        c[tt] = __builtin_amdgcn_mfma_f32_16x16x32_bf16(kf, qa, zero4, 0, 0, 0);
    }

    // additive mask bias: one aligned float4 per tile
    const float* bp = bias272 + b * 272 + lg * 4;
    #pragma unroll
    for (int tt = 0; tt < 17; tt++) {
        f32x4 bf = *(const f32x4*)&bp[tt * 16];
        c[tt][0] += bf[0]; c[tt][1] += bf[1]; c[tt][2] += bf[2]; c[tt][3] += bf[3];
    }

    // softmax: row d=lm lane-local over regs; reduce across lg via 2 shfls
    f32x4 mv = c[0];
    #pragma unroll
    for (int tt = 1; tt < 17; tt++) {
        mv[0] = fmaxf(mv[0], c[tt][0]); mv[1] = fmaxf(mv[1], c[tt][1]);
        mv[2] = fmaxf(mv[2], c[tt][2]); mv[3] = fmaxf(mv[3], c[tt][3]);
    }
    float mx = fmaxf(fmaxf(mv[0], mv[1]), fmaxf(mv[2], mv[3]));
    mx = fmaxf(mx, __shfl_xor(mx, 16));
    mx = fmaxf(mx, __shfl_xor(mx, 32));
    float sm = 0.f;
    #pragma unroll
    for (int tt = 0; tt < 17; tt++) {
        #pragma unroll
        for (int r = 0; r < 4; r++) { float e_ = __expf(c[tt][r] - mx); c[tt][r] = e_; sm += e_; }
    }
    sm += __shfl_xor(sm, 16);
    sm += __shfl_xor(sm, 32);
    float inv = 1.0f / sm;   // uniform across lg for fixed lm; applied at epilogue

    // pack P (unnormalized) to bf16 pairs
    unsigned plo[17], phi[17];
    #pragma unroll
    for (int tt = 0; tt < 17; tt++) {
        asm("v_cvt_pk_bf16_f32 %0, %1, %2" : "=v"(plo[tt]) : "v"(c[tt][0]), "v"(c[tt][1]));
        asm("v_cvt_pk_bf16_f32 %0, %1, %2" : "=v"(phi[tt]) : "v"(c[tt][2]), "v"(c[tt][3]));
    }

    // PV: in-register transpose (permlane32_swap + shfl_xor16) + V from LDS
    bool lgEven = (lane & 16) == 0;
    f32x4 o0 = zero4, o1 = zero4;
    #pragma unroll
    for (int kk = 0; kk < 9; kk++) {
        unsigned A = plo[2 * kk];
        unsigned C = phi[2 * kk];
        unsigned B = (2 * kk + 1 < 17) ? plo[2 * kk + 1] : 0u;
        unsigned D = (2 * kk + 1 < 17) ? phi[2 * kk + 1] : 0u;
        asm("v_permlane32_swap_b32 %0, %1" : "+v"(A), "+v"(B));
        asm("v_permlane32_swap_b32 %0, %1" : "+v"(C), "+v"(D));
        unsigned Ax = __shfl_xor(A, 16), Bx = __shfl_xor(B, 16);
        unsigned Cx = __shfl_xor(C, 16), Dx = __shfl_xor(D, 16);
        union { unsigned u[4]; bf16x8 v; } pa;
        pa.u[0] = lgEven ? A  : Bx;
        pa.u[1] = lgEven ? C  : Dx;
        pa.u[2] = lgEven ? Ax : B;
        pa.u[3] = lgEven ? Cx : D;
        int mr0 = kk * 8 + (lm >> 2), mr1 = mr0 + 4;
        bf16x8 v0 = *(const bf16x8*)&sbuf[VB + mr0 * 128 + ((sl0 ^ (mr0 & 15)) << 3)];
        bf16x8 v1 = *(const bf16x8*)&sbuf[VB + mr1 * 128 + ((sl0 ^ (mr1 & 15)) << 3)];
        o0 = __builtin_amdgcn_mfma_f32_16x16x32_bf16(pa.v, v0, o0, 0, 0, 0);
        o1 = __builtin_amdgcn_mfma_f32_16x16x32_bf16(pa.v, v1, o1, 0, 0, 0);
    }
    // epilogue: apply 1/sum (gather per-row inv) and store
    float invr[4];
    #pragma unroll
    for (int r = 0; r < 4; r++) invr[r] = __shfl(inv, lg * 4 + r);
    #pragma unroll
    for (int r = 0; r < 4; r++) {
        int dd = w * 16 + lg * 4 + r;
        if (dd < TD) {
            size_t nn = (size_t)b * NPIX + q * 65 + dd;
            attT[nn * 256 + g * 32 + lm]      = f2bf(o0[r] * invr[r]);
            attT[nn * 256 + g * 32 + 16 + lm] = f2bf(o1[r] * invr[r]);
        }
    }
}

// ---------------- stats over bf16 attT ----------------
__global__ void stats1_kernel(const unsigned short* __restrict__ attT, float* __restrict__ st) {
    int b = blockIdx.y;
    int t = threadIdx.x;
    int e8 = t & 31, g = e8 >> 3;
    int lane = t & 63;
    float s = 0.f, ss = 0.f;
    for (int r = blockIdx.x * 8 + (t >> 5); r < NPIX; r += gridDim.x * 8) {
        union { uint4 v; unsigned short us[8]; } u;
        u.v = *(const uint4*)&attT[((size_t)b * NPIX + r) * 256 + e8 * 8];
        #pragma unroll
        for (int j = 0; j < 8; j++) { float x = bf2f(u.us[j]); s += x; ss += x * x; }
    }
    s += __shfl_down(s, 32); ss += __shfl_down(ss, 32);
    s += __shfl_down(s, 4);  ss += __shfl_down(ss, 4);
    s += __shfl_down(s, 2);  ss += __shfl_down(ss, 2);
    s += __shfl_down(s, 1);  ss += __shfl_down(ss, 1);
    if (lane < 32 && (lane & 7) == 0) {
        atomicAdd(&st[(b * 4 + g) * 2],     s);
        atomicAdd(&st[(b * 4 + g) * 2 + 1], ss);
    }
}

// ---------------- stats over fp32 [b][C][NPIX] ----------------
__global__ void stats_kernel(const float* __restrict__ x, float* __restrict__ st, int Cg) {
    size_t len = (size_t)Cg * NPIX;
    size_t base = (size_t)blockIdx.y * len;
    const float4* x4 = reinterpret_cast<const float4*>(x + base);
    size_t len4 = len >> 2;
    float s = 0.f, ss = 0.f;
    for (size_t i = (size_t)blockIdx.x * blockDim.x + threadIdx.x; i < len4;
         i += (size_t)gridDim.x * blockDim.x) {
        float4 v = x4[i];
        s  += v.x + v.y + v.z + v.w;
        ss += v.x * v.x + v.y * v.y + v.z * v.z + v.w * v.w;
    }
    #pragma unroll
    for (int o = 32; o > 0; o >>= 1) { s += __shfl_down(s, o, 64); ss += __shfl_down(ss, o, 64); }
    __shared__ float red[4][2];
    int wid = threadIdx.x >> 6, lane = threadIdx.x & 63;
    if (lane == 0) { red[wid][0] = s; red[wid][1] = ss; }
    __syncthreads();
    if (threadIdx.x == 0) {
        float S  = red[0][0] + red[1][0] + red[2][0] + red[3][0];
        float SS = red[0][1] + red[1][1] + red[2][1] + red[3][1];
        atomicAdd(&st[blockIdx.y * 2],     S);
        atomicAdd(&st[blockIdx.y * 2 + 1], SS);
    }
}

// ---------------- z = relu(gn2(agg)) + relu(gn_sc(scr)) ----------------
__global__ void z_kernel(float* __restrict__ out, const float* __restrict__ scr,
                         const float* __restrict__ st2, const float* __restrict__ stsc,
                         const float* __restrict__ g2w, const float* __restrict__ g2b,
                         const float* __restrict__ gsw, const float* __restrict__ gsb)
{
    const float invcnt = 1.0f / (128.0f * NPIX);
    size_t total4 = (size_t)NB * COUT * (NPIX / 4);
    float4* o4 = reinterpret_cast<float4*>(out);
    const float4* s4 = reinterpret_cast<const float4*>(scr);
    for (size_t i = (size_t)blockIdx.x * blockDim.x + threadIdx.x; i < total4;
         i += (size_t)gridDim.x * blockDim.x) {
        size_t flat = i * 4;
        int c = (int)((flat / NPIX) % COUT);
        int b = (int)(flat / ((size_t)COUT * NPIX));
        int bg = b * 4 + (c >> 7);
        float2 p2 = gn_params(st2,  bg, invcnt);
        float2 ps = gn_params(stsc, bg, invcnt);
        float w2 = g2w[c] * p2.y, b2 = g2b[c] - p2.x * p2.y * g2w[c];
        float wsc = gsw[c] * ps.y, bsc = gsb[c] - ps.x * ps.y * gsw[c];
        float4 a = o4[i], r = s4[i], z;
        z.x = fmaxf(a.x * w2 + b2, 0.f) + fmaxf(r.x * wsc + bsc, 0.f);
        z.y = fmaxf(a.y * w2 + b2, 0.f) + fmaxf(r.y * wsc + bsc, 0.f);
        z.z = fmaxf(a.z * w2 + b2, 0.f) + fmaxf(r.z * wsc + bsc, 0.f);
        z.w = fmaxf(a.w * w2 + b2, 0.f) + fmaxf(r.w * wsc + bsc, 0.f);
        o4[i] = z;
    }
}

// ---------------- final gn_out ----------------
__global__ void norm_kernel(float* __restrict__ out, const float* __restrict__ st3,
                            const float* __restrict__ gw, const float* __restrict__ gb)
{
    const float invcnt = 1.0f / (128.0f * NPIX);
    size_t total4 = (size_t)NB * COUT * (NPIX / 4);
    float4* o4 = reinterpret_cast<float4*>(out);
    for (size_t i = (size_t)blockIdx.x * blockDim.x + threadIdx.x; i < total4;
         i += (size_t)gridDim.x * blockDim.x) {
        size_t flat = i * 4;
        int c = (int)((flat / NPIX) % COUT);
        int b = (int)(flat / ((size_t)COUT * NPIX));
        int bg = b * 4 + (c >> 7);
        float2 p = gn_params(st3, bg, invcnt);
        float w_ = gw[c] * p.y, b_ = gb[c] - p.x * p.y * gw[c];
        float4 a = o4[i], z;
        z.x = a.x * w_ + b_; z.y = a.y * w_ + b_; z.z = a.z * w_ + b_; z.w = a.w * w_ + b_;
        o4[i] = z;
    }
}

extern "C" void kernel_launch(void* const* d_in, const int* in_sizes, int n_in,
                              void* d_out, int out_size, void* d_ws, size_t ws_size,
                              hipStream_t stream) {
    (void)in_sizes; (void)n_in; (void)out_size; (void)ws_size;
    const float* corr     = (const float*)d_in[0];
    const int*   smask    = (const int*)  d_in[1];
    const float* W_sc     = (const float*)d_in[2];
    const float* gn_sc_w  = (const float*)d_in[3];
    const float* gn_sc_b  = (const float*)d_in[4];
    const float* W_qkv    = (const float*)d_in[5];
    const float* b_qkv    = (const float*)d_in[6];
    const float* gn1_w    = (const float*)d_in[7];
    const float* gn1_b    = (const float*)d_in[8];
    const float* W_agg    = (const float*)d_in[9];
    const float* gn2_w    = (const float*)d_in[10];
    const float* gn2_b    = (const float*)d_in[11];
    const float* gn_out_w = (const float*)d_in[12];
    const float* gn_out_b = (const float*)d_in[13];
    float* out = (float*)d_out;

    unsigned short* ws = (unsigned short*)d_ws;
    unsigned short* corrT  = ws;                           // 34,603,008 sh
    unsigned short* kbuf   = corrT  + (size_t)34603008;    // (dead space, kept for layout)
    unsigned short* vbuf   = kbuf   + (size_t)69206016;    // (dead space, kept for layout)
    unsigned short* corrpT = vbuf   + (size_t)69206016;    //  8,519,680 sh
    unsigned short* qpT    = corrpT + (size_t)8519680;     // 17,039,360 sh
    unsigned short* attT   = qpT    + (size_t)17039360;    // 17,039,360 sh
    unsigned short* wbuf   = attT   + (size_t)17039360;    //    294,912 sh
    float* bias  = (float*)(wbuf + (size_t)294912);        // 1,088 f  ([b][272])
    float* stats = bias + 1088;                            // 128 f
    float* scr   = (float*)d_ws;   // aliases corrT+kbuf head (dead by SC gemm)
    float* st_sc = stats, *st1 = stats + 32, *st2 = stats + 64, *st3 = stats + 96;
    (void)kbuf; (void)vbuf;

    const float inv1 = 1.0f / (64.0f * (float)NPIX);

    hipMemsetAsync(stats, 0, 128 * sizeof(float), stream);
    wprep_kernel<<<dim3(1152), dim3(256), 0, stream>>>(W_qkv, W_sc, W_agg, wbuf);
    mask_kernel<<<dim3(NB), dim3(320), 0, stream>>>(smask, bias);
    tpool_kernel<<<dim3(TQ, 2, NB), dim3(256), 0, stream>>>(corr, corrT, corrpT);
    // Q projection: qpT[b][n][256] = Wq x corrpT + bq
    mgemm_kernel<0,128><<<dim3(130, 2, NB), dim3(256), 0, stream>>>(
        corrpT, wbuf, NPIX, nullptr, qpT, b_qkv,
        nullptr, nullptr, nullptr, 0.f);
    // fused KV projection + attention (XCD-local (g,q) remap inside)
    attn_kernel<<<dim3(8, TQ, NB), dim3(320), 0, stream>>>(
        corrT, wbuf + 32768, b_qkv + 256, qpT, bias, attT);
    stats1_kernel<<<dim3(208, NB), dim3(256), 0, stream>>>(attT, st1);
    // agg conv with fused gn1+relu on input
    mgemm_kernel<3,256><<<dim3(130, 4, NB), dim3(256), 0, stream>>>(
        attT, wbuf + 163840, NPIX, out, nullptr, nullptr,
        st1, gn1_w, gn1_b, inv1);
    stats_kernel<<<dim3(64, 16), dim3(256), 0, stream>>>(out, st2, 128);
    // residual conv: scr = W_sc x corrpT
    mgemm_kernel<2,128><<<dim3(130, 4, NB), dim3(256), 0, stream>>>(
        corrpT, wbuf + 98304, NPIX, scr, nullptr, nullptr,
        nullptr, nullptr, nullptr, 0.f);
    stats_kernel<<<dim3(64, 16), dim3(256), 0, stream>>>(scr, st_sc, 128);
    z_kernel<<<dim3(4096), dim3(256), 0, stream>>>(out, scr, st2, st_sc, gn2_w, gn2_b, gn_sc_w, gn_sc_b);
    stats_kernel<<<dim3(64, 16), dim3(256), 0, stream>>>(out, st3, 128);
    norm_kernel<<<dim3(4096), dim3(256), 0, stream>>>(out, st3, gn_out_w, gn_out_b);
}

// Round 6
// 966.959 us; speedup vs baseline: 1.0339x; 1.0339x over previous
//
#include <hip/hip_runtime.h>
#include <stdint.h>

#define NB    4
#define TQ    256
#define TS    257
#define TD    65
#define NPIX  16640        /* TQ*TD */
#define NPADQ 264          /* padded s per q */
#define NPAD  67584        /* 256*264 */
#define COUT  512
#define HID   256

typedef __attribute__((ext_vector_type(8))) short bf16x8;
typedef __attribute__((ext_vector_type(4))) float f32x4;

// ---------------- bf16 helpers ----------------
__device__ __forceinline__ float bf2f(unsigned short u) {
    union { unsigned int i; float f; } v; v.i = ((unsigned int)u) << 16; return v.f;
}
__device__ __forceinline__ unsigned short f2bf(float x) {
    union { float f; unsigned int i; } v; v.f = x;
    unsigned int r = v.i + 0x7fffu + ((v.i >> 16) & 1u);
    return (unsigned short)(r >> 16);
}

__device__ __forceinline__ float2 gn_params(const float* st, int bg, float invcnt) {
    float mu  = st[bg * 2] * invcnt;
    float var = st[bg * 2 + 1] * invcnt - mu * mu;
    float2 r; r.x = mu; r.y = rsqrtf(var + 1e-5f); return r;
}

// ---------------- weight cast fp32 -> bf16 ----------------
__global__ void wprep_kernel(const float* __restrict__ wq, const float* __restrict__ wsc,
                             const float* __restrict__ wagg, unsigned short* __restrict__ wb) {
    int i = blockIdx.x * 256 + threadIdx.x;   // grid 1152 -> 294912
    float v;
    if (i < 98304) v = wq[i];
    else if (i < 163840) v = wsc[i - 98304];
    else v = wagg[i - 163840];
    wb[i] = f2bf(v);
}

// ---------------- mask: additive bias table [b][272] (0 or -1e9) ----------------
__global__ void mask_kernel(const int* __restrict__ sm, float* __restrict__ bias) {
    int b = blockIdx.x; int t = threadIdx.x;   // 320 threads
    if (t >= 272) return;
    float v;
    if (t == 0) v = 0.0f;
    else if (t <= 256) {
        int s = t - 1; int i = s >> 4, j = s & 15;
        v = (sm[(size_t)b * 65536 + i * 17 * 256 + j * 17] != 0) ? 0.0f : -1e9f;
    } else v = -1e9f;
    bias[b * 272 + t] = v;
}

// ---------------- fused transpose + pool ----------------
__global__ __launch_bounds__(256) void tpool_kernel(
    const float* __restrict__ corr,
    unsigned short* __restrict__ corrT,    // [b][NPAD][128]
    unsigned short* __restrict__ corrpT)   // [b][NPIX][128]
{
    int q = blockIdx.x, ch = blockIdx.y, b = blockIdx.z;
    int t = threadIdx.x;
    __shared__ unsigned short sT[264 * 66];

    {
        int laneT = t & 63; int crow = t >> 6;
        for (int c = crow; c < 64; c += 4) {
            const float* src = corr + (((size_t)b * 128 + ch * 64 + c) * 256 + q) * 257;
            for (int s = laneT; s < 257; s += 64) sT[s * 66 + c] = f2bf(src[s]);
        }
    }
    for (int idx = t; idx < 7 * 66; idx += 256) {
        int s = 257 + idx / 66, c = idx % 66;
        sT[s * 66 + c] = 0;
    }
    __syncthreads();

    {
        unsigned int* dst = (unsigned int*)corrT;
        size_t base = (size_t)b * (NPAD * 64) + (size_t)q * (264 * 64) + ch * 32;
        for (int idx = t; idx < 264 * 32; idx += 256) {
            int s = idx >> 5, cu = idx & 31;
            unsigned int v = (unsigned int)sT[s * 66 + 2 * cu] |
                             ((unsigned int)sT[s * 66 + 2 * cu + 1] << 16);
            dst[base + (size_t)s * 64 + cu] = v;
        }
    }
    {
        unsigned int* dst = (unsigned int*)corrpT;
        size_t base = (size_t)b * (NPIX * 64) + (size_t)q * (65 * 64) + ch * 32;
        for (int idx = t; idx < 65 * 32; idx += 256) {
            int d = idx >> 5, cu = idx & 31;
            float x0, x1;
            if (d == 0) {
                x0 = bf2f(sT[0 * 66 + 2 * cu]); x1 = bf2f(sT[0 * 66 + 2 * cu + 1]);
            } else {
                int dd = d - 1; int i = dd >> 3, j = dd & 7;
                int s = 1 + i * 32 + j * 2;
                int c0 = 2 * cu, c1 = 2 * cu + 1;
                x0 = 0.25f * (bf2f(sT[s*66+c0]) + bf2f(sT[(s+1)*66+c0]) +
                              bf2f(sT[(s+16)*66+c0]) + bf2f(sT[(s+17)*66+c0]));
                x1 = 0.25f * (bf2f(sT[s*66+c1]) + bf2f(sT[(s+1)*66+c1]) +
                              bf2f(sT[(s+16)*66+c1]) + bf2f(sT[(s+17)*66+c1]));
            }
            unsigned int v = (unsigned int)f2bf(x0) | ((unsigned int)f2bf(x1) << 16);
            dst[base + (size_t)d * 64 + cu] = v;
        }
    }
}

// ---------------- unified MFMA GEMM (modes 0,2,3 used) ----------------
template<int MODE, int KT>
__global__ __launch_bounds__(256) void mgemm_kernel(
    const unsigned short* __restrict__ X,
    const unsigned short* __restrict__ Wb,
    int Nn,
    float* __restrict__ Yf,
    unsigned short* __restrict__ Y16,
    const float* __restrict__ bias,
    const float* __restrict__ st, const float* __restrict__ gw, const float* __restrict__ gb,
    float invcnt)
{
    int b  = blockIdx.z;
    int n0 = blockIdx.x * 128;
    int m0 = blockIdx.y * 128;
    int t = threadIdx.x;
    int w = t >> 6, lane = t & 63;
    int lm = lane & 15, lg = lane >> 4;
    int wn = (w & 1) * 64, wm = (w >> 1) * 64;

    __shared__ __align__(16) unsigned short sX[16384];
    __shared__ __align__(16) unsigned short sW[16384];

    f32x4 acc[4][4];
    #pragma unroll
    for (int i = 0; i < 4; i++)
        #pragma unroll
        for (int j = 0; j < 4; j++) { acc[i][j][0]=0.f; acc[i][j][1]=0.f; acc[i][j][2]=0.f; acc[i][j][3]=0.f; }

    for (int kc = 0; kc < KT / 128; kc++) {
        for (int i = t; i < 2048; i += 256) {
            int r_ = i >> 4, kq = i & 15;
            uint4 xv = *(const uint4*)&X[((size_t)b * Nn + n0 + r_) * KT + kc * 128 + (kq << 3)];
            if (MODE == 3) {
                union { uint4 v; unsigned short us[8]; } u; u.v = xv;
                int c0 = kc * 128 + (kq << 3);
                float2 p = gn_params(st, b * 4 + (c0 >> 6), invcnt);
                #pragma unroll
                for (int jj = 0; jj < 8; jj++) {
                    int cc = c0 + jj;
                    float v = bf2f(u.us[jj]);
                    v = fmaxf((v - p.x) * p.y * gw[cc] + gb[cc], 0.0f);
                    u.us[jj] = f2bf(v);
                }
                xv = u.v;
            }
            *(uint4*)&sX[r_ * 128 + ((kq ^ (r_ & 15)) << 3)] = xv;
            uint4 wv = *(const uint4*)&Wb[((size_t)(m0 + r_)) * KT + kc * 128 + (kq << 3)];
            *(uint4*)&sW[r_ * 128 + ((kq ^ (r_ & 15)) << 3)] = wv;
        }
        __syncthreads();
        #pragma unroll
        for (int kk = 0; kk < 4; kk++) {
            int kg = (kk << 2) | lg;
            bf16x8 af[4], bw[4];
            #pragma unroll
            for (int ii = 0; ii < 4; ii++)
                af[ii] = *(const bf16x8*)&sX[(wn + ii * 16 + lm) * 128 + ((kg ^ lm) << 3)];
            #pragma unroll
            for (int jj = 0; jj < 4; jj++)
                bw[jj] = *(const bf16x8*)&sW[(wm + jj * 16 + lm) * 128 + ((kg ^ lm) << 3)];
            #pragma unroll
            for (int ii = 0; ii < 4; ii++)
                #pragma unroll
                for (int jj = 0; jj < 4; jj++) {
                    if (MODE == 0)
                        acc[ii][jj] = __builtin_amdgcn_mfma_f32_16x16x32_bf16(bw[jj], af[ii], acc[ii][jj], 0,0,0);
                    else
                        acc[ii][jj] = __builtin_amdgcn_mfma_f32_16x16x32_bf16(af[ii], bw[jj], acc[ii][jj], 0,0,0);
                }
        }
        __syncthreads();
    }

    if (MODE == 0) {
        #pragma unroll
        for (int ii = 0; ii < 4; ii++) {
            int n = n0 + wn + ii * 16 + lm;
            #pragma unroll
            for (int jj = 0; jj < 4; jj++) {
                int mb = m0 + wm + jj * 16 + lg * 4;
                union { unsigned short us[4]; uint2 v; } pk;
                #pragma unroll
                for (int r = 0; r < 4; r++) pk.us[r] = f2bf(acc[ii][jj][r] + bias[mb + r]);
                *(uint2*)&Y16[((size_t)b * NPIX + n) * 256 + mb] = pk.v;
            }
        }
    } else {
        #pragma unroll
        for (int ii = 0; ii < 4; ii++) {
            int nb = n0 + wn + ii * 16 + lg * 4;
            #pragma unroll
            for (int jj = 0; jj < 4; jj++) {
                int m = m0 + wm + jj * 16 + lm;
                *(f32x4*)&Yf[((size_t)b * COUT + m) * NPIX + nb] = acc[ii][jj];
            }
        }
    }
}

// ---------------- fused KV-projection + MFMA attention ----------------
// grid (8, 256, 4); 320 threads = 5 waves. (g,q) REMAPPED from flat id so that all
// 8 g-blocks (and all 4 b's) sharing one corrT q-tile land on the SAME XCD:
//   lin = by*8+bx; xcd = lin&7; idx = lin>>3; q = xcd*32 + (idx&31); g = idx>>5.
// (Verified round 5: FETCH 303 MB -> 53 MB.) Phase-1 uses the plain (non-prefetch)
// loads from round 3 — the prefetch variant cost +20 VGPR, crossed the 64-VGPR
// occupancy granule and halved resident waves (occupancy 24.9 -> 15.4, dur +30us).
// Phase 1: K[264s][32e], V[32ch][264s] in LDS from corrT tile x W_kv (L1-hot).
// Phase 2: QK^T, bias, softmax, in-reg P transpose, PV.
// LDS: K at [0,17408) = [272 s][32 e]; V at [17408,35840) = [9 kk][32 ch][32 s].
// Swizzle: 16B-slot sl within each 256B macro-row stored at sl ^ (mr&15) (region-relative mr).
__global__ __launch_bounds__(320, 3) void attn_kernel(
    const unsigned short* __restrict__ corrT, // [b][NPAD][128]
    const unsigned short* __restrict__ wkv,   // [512][128] bf16: rows 0..255 Wk, 256..511 Wv
    const float* __restrict__ bkv,            // [512] fp32 bias: K then V
    const unsigned short* __restrict__ qpT,   // [b][NPIX][256]
    const float* __restrict__ bias272,        // [b][272] additive mask bias
    unsigned short* __restrict__ attT)        // [b][NPIX][256]
{
    int lin = blockIdx.y * 8 + blockIdx.x;
    int xcd = lin & 7, idx = lin >> 3;
    int q = (xcd << 5) | (idx & 31);
    int g = idx >> 5;
    int b = blockIdx.z;
    int t = threadIdx.x;
    int w = t >> 6, lane = t & 63;
    int lm = lane & 15, lg = lane >> 4;

    __shared__ __align__(16) unsigned short sbuf[17920];   // 35840 B: K then V
    const int VB = 8704;                                    // V base in shorts

    // Q frag (B operand: lane holds Q[d=16w+lm][e=g*32+lg*8+j]); clamp + zero d>=65
    int d = w * 16 + lm;
    int dc = d < 64 ? d : 64;
    bf16x8 qa = *(const bf16x8*)&qpT[((size_t)b * NPIX + q * 65 + dc) * 256 + g * 32 + lg * 8];
    if (d >= TD) { bf16x8 z = {}; qa = z; }

    // ---- phase 1: in-block K/V projection (plain loads, round-3 form) ----
    bf16x8 wkf[2][4], wvf[2][4];
    #pragma unroll
    for (int et = 0; et < 2; et++)
        #pragma unroll
        for (int ks = 0; ks < 4; ks++) {
            wkf[et][ks] = *(const bf16x8*)&wkv[(size_t)(g * 32 + et * 16 + lm) * 128 + ks * 32 + lg * 8];
            wvf[et][ks] = *(const bf16x8*)&wkv[(size_t)(256 + g * 32 + et * 16 + lm) * 128 + ks * 32 + lg * 8];
        }
    float bk_[2][4], bv_[2];
    #pragma unroll
    for (int et = 0; et < 2; et++) {
        #pragma unroll
        for (int r = 0; r < 4; r++) bk_[et][r] = bkv[g * 32 + et * 16 + lg * 4 + r];
        bv_[et] = bkv[256 + g * 32 + et * 16 + lm];
    }

    const unsigned short* cbase = corrT + ((size_t)b * NPAD + (size_t)q * 264) * 128;
    f32x4 zero4 = {0.f, 0.f, 0.f, 0.f};

    for (int sti = w; sti < 17; sti += 5) {
        int srow = sti * 16 + lm; if (srow > 263) srow = 263;   // pad rows are zeroed
        bf16x8 ct[4];
        #pragma unroll
        for (int ks = 0; ks < 4; ks++)
            ct[ks] = *(const bf16x8*)&cbase[(size_t)srow * 128 + ks * 32 + lg * 8];
        f32x4 ak0 = zero4, ak1 = zero4, av0 = zero4, av1 = zero4;
        #pragma unroll
        for (int ks = 0; ks < 4; ks++) {
            ak0 = __builtin_amdgcn_mfma_f32_16x16x32_bf16(wkf[0][ks], ct[ks], ak0, 0, 0, 0);
            ak1 = __builtin_amdgcn_mfma_f32_16x16x32_bf16(wkf[1][ks], ct[ks], ak1, 0, 0, 0);
            av0 = __builtin_amdgcn_mfma_f32_16x16x32_bf16(ct[ks], wvf[0][ks], av0, 0, 0, 0);
            av1 = __builtin_amdgcn_mfma_f32_16x16x32_bf16(ct[ks], wvf[1][ks], av1, 0, 0, 0);
        }
        // K writes: lane holds K[e=et*16+lg*4+r][s=sti*16+lm]
        {
            int s = sti * 16 + lm;
            #pragma unroll
            for (int et = 0; et < 2; et++) {
                unsigned u = (unsigned)(s * 64 + et * 32 + lg * 8);
                unsigned mr = u >> 8, sl = (u >> 4) & 15;
                unsigned us = (u & ~0xF0u) | ((sl ^ (mr & 15)) << 4);
                union { unsigned short e[4]; uint2 v; } pk;
                f32x4 a = et ? ak1 : ak0;
                #pragma unroll
                for (int r = 0; r < 4; r++) pk.e[r] = f2bf(a[r] + bk_[et][r]);
                *(uint2*)((char*)sbuf + us) = pk.v;
            }
        }
        // V writes: lane holds V[ch=et*16+lm][s=sti*16+lg*4+r]
        {
            int s0 = sti * 16 + lg * 4;
            unsigned vb_off = (unsigned)((s0 >> 5) * 2048 + (s0 & 31) * 2);
            #pragma unroll
            for (int et = 0; et < 2; et++) {
                int ch = et * 16 + lm;
                unsigned ov = vb_off + (unsigned)ch * 64u;
                unsigned mr = ov >> 8, sl = (ov >> 4) & 15;
                unsigned ovs = (ov & ~0xF0u) | ((sl ^ (mr & 15)) << 4);
                union { unsigned short e[4]; uint2 v; } pk;
                f32x4 a = et ? av1 : av0;
                #pragma unroll
                for (int r = 0; r < 4; r++) pk.e[r] = f2bf(a[r] + bv_[et]);
                *(uint2*)((char*)sbuf + 17408 + ovs) = pk.v;
            }
        }
    }
    // zero-fill V window s in [272,288)
    if (t < 128) {
        int ch = t >> 2, j = t & 3;
        unsigned ov = 16384u + (unsigned)ch * 64u + 32u + (unsigned)j * 8u;
        unsigned mr = ov >> 8, sl = (ov >> 4) & 15;
        unsigned ovs = (ov & ~0xF0u) | ((sl ^ (mr & 15)) << 4);
        uint2 z2; z2.x = 0u; z2.y = 0u;
        *(uint2*)((char*)sbuf + 17408 + ovs) = z2;
    }
    __syncthreads();

    // ---- phase 2: QK^T from LDS: c[tt] holds S^T[s=16tt+4lg+r][d=lm] ----
    f32x4 c[17];
    int sl0 = ((lm & 3) << 2) | lg;
    #pragma unroll
    for (int tt = 0; tt < 17; tt++) {
        int mr = tt * 4 + (lm >> 2);
        bf16x8 kf = *(const bf16x8*)&sbuf[mr * 128 + ((sl0 ^ (mr & 15)) << 3)];
        c[tt] = __builtin_amdgcn_mfma_f32_16x16x32_bf16(kf, qa, zero4, 0, 0, 0);
    }

    // additive mask bias: one aligned float4 per tile
    const float* bp = bias272 + b * 272 + lg * 4;
    #pragma unroll
    for (int tt = 0; tt < 17; tt++) {
        f32x4 bf = *(const f32x4*)&bp[tt * 16];
        c[tt][0] += bf[0]; c[tt][1] += bf[1]; c[tt][2] += bf[2]; c[tt][3] += bf[3];
    }

    // softmax: row d=lm lane-local over regs; reduce across lg via 2 shfls
    f32x4 mv = c[0];
    #pragma unroll
    for (int tt = 1; tt < 17; tt++) {
        mv[0] = fmaxf(mv[0], c[tt][0]); mv[1] = fmaxf(mv[1], c[tt][1]);
        mv[2] = fmaxf(mv[2], c[tt][2]); mv[3] = fmaxf(mv[3], c[tt][3]);
    }
    float mx = fmaxf(fmaxf(mv[0], mv[1]), fmaxf(mv[2], mv[3]));
    mx = fmaxf(mx, __shfl_xor(mx, 16));
    mx = fmaxf(mx, __shfl_xor(mx, 32));
    float sm = 0.f;
    #pragma unroll
    for (int tt = 0; tt < 17; tt++) {
        #pragma unroll
        for (int r = 0; r < 4; r++) { float e_ = __expf(c[tt][r] - mx); c[tt][r] = e_; sm += e_; }
    }
    sm += __shfl_xor(sm, 16);
    sm += __shfl_xor(sm, 32);
    float inv = 1.0f / sm;   // uniform across lg for fixed lm; applied at epilogue

    // pack P (unnormalized) to bf16 pairs
    unsigned plo[17], phi[17];
    #pragma unroll
    for (int tt = 0; tt < 17; tt++) {
        asm("v_cvt_pk_bf16_f32 %0, %1, %2" : "=v"(plo[tt]) : "v"(c[tt][0]), "v"(c[tt][1]));
        asm("v_cvt_pk_bf16_f32 %0, %1, %2" : "=v"(phi[tt]) : "v"(c[tt][2]), "v"(c[tt][3]));
    }

    // PV: in-register transpose (permlane32_swap + shfl_xor16) + V from LDS
    bool lgEven = (lane & 16) == 0;
    f32x4 o0 = zero4, o1 = zero4;
    #pragma unroll
    for (int kk = 0; kk < 9; kk++) {
        unsigned A = plo[2 * kk];
        unsigned C = phi[2 * kk];
        unsigned B = (2 * kk + 1 < 17) ? plo[2 * kk + 1] : 0u;
        unsigned D = (2 * kk + 1 < 17) ? phi[2 * kk + 1] : 0u;
        asm("v_permlane32_swap_b32 %0, %1" : "+v"(A), "+v"(B));
        asm("v_permlane32_swap_b32 %0, %1" : "+v"(C), "+v"(D));
        unsigned Ax = __shfl_xor(A, 16), Bx = __shfl_xor(B, 16);
        unsigned Cx = __shfl_xor(C, 16), Dx = __shfl_xor(D, 16);
        union { unsigned u[4]; bf16x8 v; } pa;
        pa.u[0] = lgEven ? A  : Bx;
        pa.u[1] = lgEven ? C  : Dx;
        pa.u[2] = lgEven ? Ax : B;
        pa.u[3] = lgEven ? Cx : D;
        int mr0 = kk * 8 + (lm >> 2), mr1 = mr0 + 4;
        bf16x8 v0 = *(const bf16x8*)&sbuf[VB + mr0 * 128 + ((sl0 ^ (mr0 & 15)) << 3)];
        bf16x8 v1 = *(const bf16x8*)&sbuf[VB + mr1 * 128 + ((sl0 ^ (mr1 & 15)) << 3)];
        o0 = __builtin_amdgcn_mfma_f32_16x16x32_bf16(pa.v, v0, o0, 0, 0, 0);
        o1 = __builtin_amdgcn_mfma_f32_16x16x32_bf16(pa.v, v1, o1, 0, 0, 0);
    }
    // epilogue: apply 1/sum (gather per-row inv) and store
    float invr[4];
    #pragma unroll
    for (int r = 0; r < 4; r++) invr[r] = __shfl(inv, lg * 4 + r);
    #pragma unroll
    for (int r = 0; r < 4; r++) {
        int dd = w * 16 + lg * 4 + r;
        if (dd < TD) {
            size_t nn = (size_t)b * NPIX + q * 65 + dd;
            attT[nn * 256 + g * 32 + lm]      = f2bf(o0[r] * invr[r]);
            attT[nn * 256 + g * 32 + 16 + lm] = f2bf(o1[r] * invr[r]);
        }
    }
}

// ---------------- stats over bf16 attT ----------------
__global__ void stats1_kernel(const unsigned short* __restrict__ attT, float* __restrict__ st) {
    int b = blockIdx.y;
    int t = threadIdx.x;
    int e8 = t & 31, g = e8 >> 3;
    int lane = t & 63;
    float s = 0.f, ss = 0.f;
    for (int r = blockIdx.x * 8 + (t >> 5); r < NPIX; r += gridDim.x * 8) {
        union { uint4 v; unsigned short us[8]; } u;
        u.v = *(const uint4*)&attT[((size_t)b * NPIX + r) * 256 + e8 * 8];
        #pragma unroll
        for (int j = 0; j < 8; j++) { float x = bf2f(u.us[j]); s += x; ss += x * x; }
    }
    s += __shfl_down(s, 32); ss += __shfl_down(ss, 32);
    s += __shfl_down(s, 4);  ss += __shfl_down(ss, 4);
    s += __shfl_down(s, 2);  ss += __shfl_down(ss, 2);
    s += __shfl_down(s, 1);  ss += __shfl_down(ss, 1);
    if (lane < 32 && (lane & 7) == 0) {
        atomicAdd(&st[(b * 4 + g) * 2],     s);
        atomicAdd(&st[(b * 4 + g) * 2 + 1], ss);
    }
}

// ---------------- stats over fp32 [b][C][NPIX] ----------------
__global__ void stats_kernel(const float* __restrict__ x, float* __restrict__ st, int Cg) {
    size_t len = (size_t)Cg * NPIX;
    size_t base = (size_t)blockIdx.y * len;
    const float4* x4 = reinterpret_cast<const float4*>(x + base);
    size_t len4 = len >> 2;
    float s = 0.f, ss = 0.f;
    for (size_t i = (size_t)blockIdx.x * blockDim.x + threadIdx.x; i < len4;
         i += (size_t)gridDim.x * blockDim.x) {
        float4 v = x4[i];
        s  += v.x + v.y + v.z + v.w;
        ss += v.x * v.x + v.y * v.y + v.z * v.z + v.w * v.w;
    }
    #pragma unroll
    for (int o = 32; o > 0; o >>= 1) { s += __shfl_down(s, o, 64); ss += __shfl_down(ss, o, 64); }
    __shared__ float red[4][2];
    int wid = threadIdx.x >> 6, lane = threadIdx.x & 63;
    if (lane == 0) { red[wid][0] = s; red[wid][1] = ss; }
    __syncthreads();
    if (threadIdx.x == 0) {
        float S  = red[0][0] + red[1][0] + red[2][0] + red[3][0];
        float SS = red[0][1] + red[1][1] + red[2][1] + red[3][1];
        atomicAdd(&st[blockIdx.y * 2],     S);
        atomicAdd(&st[blockIdx.y * 2 + 1], SS);
    }
}

// ---------------- z = relu(gn2(agg)) + relu(gn_sc(scr)) ----------------
__global__ void z_kernel(float* __restrict__ out, const float* __restrict__ scr,
                         const float* __restrict__ st2, const float* __restrict__ stsc,
                         const float* __restrict__ g2w, const float* __restrict__ g2b,
                         const float* __restrict__ gsw, const float* __restrict__ gsb)
{
    const float invcnt = 1.0f / (128.0f * NPIX);
    size_t total4 = (size_t)NB * COUT * (NPIX / 4);
    float4* o4 = reinterpret_cast<float4*>(out);
    const float4* s4 = reinterpret_cast<const float4*>(scr);
    for (size_t i = (size_t)blockIdx.x * blockDim.x + threadIdx.x; i < total4;
         i += (size_t)gridDim.x * blockDim.x) {
        size_t flat = i * 4;
        int c = (int)((flat / NPIX) % COUT);
        int b = (int)(flat / ((size_t)COUT * NPIX));
        int bg = b * 4 + (c >> 7);
        float2 p2 = gn_params(st2,  bg, invcnt);
        float2 ps = gn_params(stsc, bg, invcnt);
        float w2 = g2w[c] * p2.y, b2 = g2b[c] - p2.x * p2.y * g2w[c];
        float wsc = gsw[c] * ps.y, bsc = gsb[c] - ps.x * ps.y * gsw[c];
        float4 a = o4[i], r = s4[i], z;
        z.x = fmaxf(a.x * w2 + b2, 0.f) + fmaxf(r.x * wsc + bsc, 0.f);
        z.y = fmaxf(a.y * w2 + b2, 0.f) + fmaxf(r.y * wsc + bsc, 0.f);
        z.z = fmaxf(a.z * w2 + b2, 0.f) + fmaxf(r.z * wsc + bsc, 0.f);
        z.w = fmaxf(a.w * w2 + b2, 0.f) + fmaxf(r.w * wsc + bsc, 0.f);
        o4[i] = z;
    }
}

// ---------------- final gn_out ----------------
__global__ void norm_kernel(float* __restrict__ out, const float* __restrict__ st3,
                            const float* __restrict__ gw, const float* __restrict__ gb)
{
    const float invcnt = 1.0f / (128.0f * NPIX);
    size_t total4 = (size_t)NB * COUT * (NPIX / 4);
    float4* o4 = reinterpret_cast<float4*>(out);
    for (size_t i = (size_t)blockIdx.x * blockDim.x + threadIdx.x; i < total4;
         i += (size_t)gridDim.x * blockDim.x) {
        size_t flat = i * 4;
        int c = (int)((flat / NPIX) % COUT);
        int b = (int)(flat / ((size_t)COUT * NPIX));
        int bg = b * 4 + (c >> 7);
        float2 p = gn_params(st3, bg, invcnt);
        float w_ = gw[c] * p.y, b_ = gb[c] - p.x * p.y * gw[c];
        float4 a = o4[i], z;
        z.x = a.x * w_ + b_; z.y = a.y * w_ + b_; z.z = a.z * w_ + b_; z.w = a.w * w_ + b_;
        o4[i] = z;
    }
}

extern "C" void kernel_launch(void* const* d_in, const int* in_sizes, int n_in,
                              void* d_out, int out_size, void* d_ws, size_t ws_size,
                              hipStream_t stream) {
    (void)in_sizes; (void)n_in; (void)out_size; (void)ws_size;
    const float* corr     = (const float*)d_in[0];
    const int*   smask    = (const int*)  d_in[1];
    const float* W_sc     = (const float*)d_in[2];
    const float* gn_sc_w  = (const float*)d_in[3];
    const float* gn_sc_b  = (const float*)d_in[4];
    const float* W_qkv    = (const float*)d_in[5];
    const float* b_qkv    = (const float*)d_in[6];
    const float* gn1_w    = (const float*)d_in[7];
    const float* gn1_b    = (const float*)d_in[8];
    const float* W_agg    = (const float*)d_in[9];
    const float* gn2_w    = (const float*)d_in[10];
    const float* gn2_b    = (const float*)d_in[11];
    const float* gn_out_w = (const float*)d_in[12];
    const float* gn_out_b = (const float*)d_in[13];
    float* out = (float*)d_out;

    unsigned short* ws = (unsigned short*)d_ws;
    unsigned short* corrT  = ws;                           // 34,603,008 sh
    unsigned short* kbuf   = corrT  + (size_t)34603008;    // (dead space, kept for layout)
    unsigned short* vbuf   = kbuf   + (size_t)69206016;    // (dead space, kept for layout)
    unsigned short* corrpT = vbuf   + (size_t)69206016;    //  8,519,680 sh
    unsigned short* qpT    = corrpT + (size_t)8519680;     // 17,039,360 sh
    unsigned short* attT   = qpT    + (size_t)17039360;    // 17,039,360 sh
    unsigned short* wbuf   = attT   + (size_t)17039360;    //    294,912 sh
    float* bias  = (float*)(wbuf + (size_t)294912);        // 1,088 f  ([b][272])
    float* stats = bias + 1088;                            // 128 f
    float* scr   = (float*)d_ws;   // aliases corrT+kbuf head (dead by SC gemm)
    float* st_sc = stats, *st1 = stats + 32, *st2 = stats + 64, *st3 = stats + 96;
    (void)kbuf; (void)vbuf;

    const float inv1 = 1.0f / (64.0f * (float)NPIX);

    hipMemsetAsync(stats, 0, 128 * sizeof(float), stream);
    wprep_kernel<<<dim3(1152), dim3(256), 0, stream>>>(W_qkv, W_sc, W_agg, wbuf);
    mask_kernel<<<dim3(NB), dim3(320), 0, stream>>>(smask, bias);
    tpool_kernel<<<dim3(TQ, 2, NB), dim3(256), 0, stream>>>(corr, corrT, corrpT);
    // Q projection: qpT[b][n][256] = Wq x corrpT + bq
    mgemm_kernel<0,128><<<dim3(130, 2, NB), dim3(256), 0, stream>>>(
        corrpT, wbuf, NPIX, nullptr, qpT, b_qkv,
        nullptr, nullptr, nullptr, 0.f);
    // fused KV projection + attention (XCD-local (g,q) remap inside)
    attn_kernel<<<dim3(8, TQ, NB), dim3(320), 0, stream>>>(
        corrT, wbuf + 32768, b_qkv + 256, qpT, bias, attT);
    stats1_kernel<<<dim3(208, NB), dim3(256), 0, stream>>>(attT, st1);
    // agg conv with fused gn1+relu on input
    mgemm_kernel<3,256><<<dim3(130, 4, NB), dim3(256), 0, stream>>>(
        attT, wbuf + 163840, NPIX, out, nullptr, nullptr,
        st1, gn1_w, gn1_b, inv1);
    stats_kernel<<<dim3(64, 16), dim3(256), 0, stream>>>(out, st2, 128);
    // residual conv: scr = W_sc x corrpT
    mgemm_kernel<2,128><<<dim3(130, 4, NB), dim3(256), 0, stream>>>(
        corrpT, wbuf + 98304, NPIX, scr, nullptr, nullptr,
        nullptr, nullptr, nullptr, 0.f);
    stats_kernel<<<dim3(64, 16), dim3(256), 0, stream>>>(scr, st_sc, 128);
    z_kernel<<<dim3(4096), dim3(256), 0, stream>>>(out, scr, st2, st_sc, gn2_w, gn2_b, gn_sc_w, gn_sc_b);
    stats_kernel<<<dim3(64, 16), dim3(256), 0, stream>>>(out, st3, 128);
    norm_kernel<<<dim3(4096), dim3(256), 0, stream>>>(out, st3, gn_out_w, gn_out_b);
}

// Round 7
// 940.569 us; speedup vs baseline: 1.0629x; 1.0281x over previous
//
#include <hip/hip_runtime.h>
#include <stdint.h>

#define NB    4
#define TQ    256
#define TS    257
#define TD    65
#define NPIX  16640        /* TQ*TD */
#define NPADQ 264          /* padded s per q */
#define NPAD  67584        /* 256*264 */
#define COUT  512
#define HID   256

typedef __attribute__((ext_vector_type(8))) short bf16x8;
typedef __attribute__((ext_vector_type(4))) float f32x4;

// ---------------- bf16 helpers ----------------
__device__ __forceinline__ float bf2f(unsigned short u) {
    union { unsigned int i; float f; } v; v.i = ((unsigned int)u) << 16; return v.f;
}
__device__ __forceinline__ unsigned short f2bf(float x) {
    union { float f; unsigned int i; } v; v.f = x;
    unsigned int r = v.i + 0x7fffu + ((v.i >> 16) & 1u);
    return (unsigned short)(r >> 16);
}

__device__ __forceinline__ float2 gn_params(const float* st, int bg, float invcnt) {
    float mu  = st[bg * 2] * invcnt;
    float var = st[bg * 2 + 1] * invcnt - mu * mu;
    float2 r; r.x = mu; r.y = rsqrtf(var + 1e-5f); return r;
}

// ---------------- weight cast fp32 -> bf16 ----------------
__global__ void wprep_kernel(const float* __restrict__ wq, const float* __restrict__ wsc,
                             const float* __restrict__ wagg, unsigned short* __restrict__ wb) {
    int i = blockIdx.x * 256 + threadIdx.x;   // grid 1152 -> 294912
    float v;
    if (i < 98304) v = wq[i];
    else if (i < 163840) v = wsc[i - 98304];
    else v = wagg[i - 163840];
    wb[i] = f2bf(v);
}

// ---------------- mask: additive bias table [b][272] (0 or -1e9) ----------------
__global__ void mask_kernel(const int* __restrict__ sm, float* __restrict__ bias) {
    int b = blockIdx.x; int t = threadIdx.x;   // 320 threads
    if (t >= 272) return;
    float v;
    if (t == 0) v = 0.0f;
    else if (t <= 256) {
        int s = t - 1; int i = s >> 4, j = s & 15;
        v = (sm[(size_t)b * 65536 + i * 17 * 256 + j * 17] != 0) ? 0.0f : -1e9f;
    } else v = -1e9f;
    bias[b * 272 + t] = v;
}

// ---------------- fused transpose + pool ----------------
__global__ __launch_bounds__(256) void tpool_kernel(
    const float* __restrict__ corr,
    unsigned short* __restrict__ corrT,    // [b][NPAD][128]
    unsigned short* __restrict__ corrpT)   // [b][NPIX][128]
{
    int q = blockIdx.x, ch = blockIdx.y, b = blockIdx.z;
    int t = threadIdx.x;
    __shared__ unsigned short sT[264 * 66];

    {
        int laneT = t & 63; int crow = t >> 6;
        for (int c = crow; c < 64; c += 4) {
            const float* src = corr + (((size_t)b * 128 + ch * 64 + c) * 256 + q) * 257;
            for (int s = laneT; s < 257; s += 64) sT[s * 66 + c] = f2bf(src[s]);
        }
    }
    for (int idx = t; idx < 7 * 66; idx += 256) {
        int s = 257 + idx / 66, c = idx % 66;
        sT[s * 66 + c] = 0;
    }
    __syncthreads();

    {
        unsigned int* dst = (unsigned int*)corrT;
        size_t base = (size_t)b * (NPAD * 64) + (size_t)q * (264 * 64) + ch * 32;
        for (int idx = t; idx < 264 * 32; idx += 256) {
            int s = idx >> 5, cu = idx & 31;
            unsigned int v = (unsigned int)sT[s * 66 + 2 * cu] |
                             ((unsigned int)sT[s * 66 + 2 * cu + 1] << 16);
            dst[base + (size_t)s * 64 + cu] = v;
        }
    }
    {
        unsigned int* dst = (unsigned int*)corrpT;
        size_t base = (size_t)b * (NPIX * 64) + (size_t)q * (65 * 64) + ch * 32;
        for (int idx = t; idx < 65 * 32; idx += 256) {
            int d = idx >> 5, cu = idx & 31;
            float x0, x1;
            if (d == 0) {
                x0 = bf2f(sT[0 * 66 + 2 * cu]); x1 = bf2f(sT[0 * 66 + 2 * cu + 1]);
            } else {
                int dd = d - 1; int i = dd >> 3, j = dd & 7;
                int s = 1 + i * 32 + j * 2;
                int c0 = 2 * cu, c1 = 2 * cu + 1;
                x0 = 0.25f * (bf2f(sT[s*66+c0]) + bf2f(sT[(s+1)*66+c0]) +
                              bf2f(sT[(s+16)*66+c0]) + bf2f(sT[(s+17)*66+c0]));
                x1 = 0.25f * (bf2f(sT[s*66+c1]) + bf2f(sT[(s+1)*66+c1]) +
                              bf2f(sT[(s+16)*66+c1]) + bf2f(sT[(s+17)*66+c1]));
            }
            unsigned int v = (unsigned int)f2bf(x0) | ((unsigned int)f2bf(x1) << 16);
            dst[base + (size_t)d * 64 + cu] = v;
        }
    }
}

// ---------------- unified MFMA GEMM (modes 0,2,3 used) ----------------
// MODE 2/3 additionally accumulate GroupNorm stats of their own output into stacc:
// an m-block of 128 rows lies entirely within one group (bg = b*4 + blockIdx.y),
// so the whole block reduces to ONE (sum, sumsq) pair -> 2 atomics. This removes
// the separate 136MB-re-read stats passes.
template<int MODE, int KT>
__global__ __launch_bounds__(256) void mgemm_kernel(
    const unsigned short* __restrict__ X,
    const unsigned short* __restrict__ Wb,
    int Nn,
    float* __restrict__ Yf,
    unsigned short* __restrict__ Y16,
    const float* __restrict__ bias,
    const float* __restrict__ st, const float* __restrict__ gw, const float* __restrict__ gb,
    float invcnt,
    float* __restrict__ stacc)
{
    int b  = blockIdx.z;
    int n0 = blockIdx.x * 128;
    int m0 = blockIdx.y * 128;
    int t = threadIdx.x;
    int w = t >> 6, lane = t & 63;
    int lm = lane & 15, lg = lane >> 4;
    int wn = (w & 1) * 64, wm = (w >> 1) * 64;

    __shared__ __align__(16) unsigned short sX[16384];
    __shared__ __align__(16) unsigned short sW[16384];
    __shared__ float red2[4][2];

    f32x4 acc[4][4];
    #pragma unroll
    for (int i = 0; i < 4; i++)
        #pragma unroll
        for (int j = 0; j < 4; j++) { acc[i][j][0]=0.f; acc[i][j][1]=0.f; acc[i][j][2]=0.f; acc[i][j][3]=0.f; }

    for (int kc = 0; kc < KT / 128; kc++) {
        for (int i = t; i < 2048; i += 256) {
            int r_ = i >> 4, kq = i & 15;
            uint4 xv = *(const uint4*)&X[((size_t)b * Nn + n0 + r_) * KT + kc * 128 + (kq << 3)];
            if (MODE == 3) {
                union { uint4 v; unsigned short us[8]; } u; u.v = xv;
                int c0 = kc * 128 + (kq << 3);
                float2 p = gn_params(st, b * 4 + (c0 >> 6), invcnt);
                #pragma unroll
                for (int jj = 0; jj < 8; jj++) {
                    int cc = c0 + jj;
                    float v = bf2f(u.us[jj]);
                    v = fmaxf((v - p.x) * p.y * gw[cc] + gb[cc], 0.0f);
                    u.us[jj] = f2bf(v);
                }
                xv = u.v;
            }
            *(uint4*)&sX[r_ * 128 + ((kq ^ (r_ & 15)) << 3)] = xv;
            uint4 wv = *(const uint4*)&Wb[((size_t)(m0 + r_)) * KT + kc * 128 + (kq << 3)];
            *(uint4*)&sW[r_ * 128 + ((kq ^ (r_ & 15)) << 3)] = wv;
        }
        __syncthreads();
        #pragma unroll
        for (int kk = 0; kk < 4; kk++) {
            int kg = (kk << 2) | lg;
            bf16x8 af[4], bw[4];
            #pragma unroll
            for (int ii = 0; ii < 4; ii++)
                af[ii] = *(const bf16x8*)&sX[(wn + ii * 16 + lm) * 128 + ((kg ^ lm) << 3)];
            #pragma unroll
            for (int jj = 0; jj < 4; jj++)
                bw[jj] = *(const bf16x8*)&sW[(wm + jj * 16 + lm) * 128 + ((kg ^ lm) << 3)];
            #pragma unroll
            for (int ii = 0; ii < 4; ii++)
                #pragma unroll
                for (int jj = 0; jj < 4; jj++) {
                    if (MODE == 0)
                        acc[ii][jj] = __builtin_amdgcn_mfma_f32_16x16x32_bf16(bw[jj], af[ii], acc[ii][jj], 0,0,0);
                    else
                        acc[ii][jj] = __builtin_amdgcn_mfma_f32_16x16x32_bf16(af[ii], bw[jj], acc[ii][jj], 0,0,0);
                }
        }
        __syncthreads();
    }

    if (MODE == 0) {
        #pragma unroll
        for (int ii = 0; ii < 4; ii++) {
            int n = n0 + wn + ii * 16 + lm;
            #pragma unroll
            for (int jj = 0; jj < 4; jj++) {
                int mb = m0 + wm + jj * 16 + lg * 4;
                union { unsigned short us[4]; uint2 v; } pk;
                #pragma unroll
                for (int r = 0; r < 4; r++) pk.us[r] = f2bf(acc[ii][jj][r] + bias[mb + r]);
                *(uint2*)&Y16[((size_t)b * NPIX + n) * 256 + mb] = pk.v;
            }
        }
    } else {
        float s = 0.f, ss = 0.f;
        #pragma unroll
        for (int ii = 0; ii < 4; ii++) {
            int nb = n0 + wn + ii * 16 + lg * 4;
            #pragma unroll
            for (int jj = 0; jj < 4; jj++) {
                int m = m0 + wm + jj * 16 + lm;
                *(f32x4*)&Yf[((size_t)b * COUT + m) * NPIX + nb] = acc[ii][jj];
                #pragma unroll
                for (int r = 0; r < 4; r++) { float v = acc[ii][jj][r]; s += v; ss += v * v; }
            }
        }
        // block stat reduce (whole block is one (b, group))
        #pragma unroll
        for (int o = 32; o > 0; o >>= 1) { s += __shfl_down(s, o, 64); ss += __shfl_down(ss, o, 64); }
        if (lane == 0) { red2[w][0] = s; red2[w][1] = ss; }
        __syncthreads();
        if (t == 0) {
            float S  = red2[0][0] + red2[1][0] + red2[2][0] + red2[3][0];
            float SS = red2[0][1] + red2[1][1] + red2[2][1] + red2[3][1];
            int bg = b * 4 + blockIdx.y;
            atomicAdd(&stacc[bg * 2],     S);
            atomicAdd(&stacc[bg * 2 + 1], SS);
        }
    }
}

// ---------------- fused KV-projection + MFMA attention ----------------
// grid (8, 256, 4); 320 threads = 5 waves. (g,q) REMAPPED from flat id so that all
// 8 g-blocks (and all 4 b's) sharing one corrT q-tile land on the SAME XCD
// (verified: FETCH 303 MB -> 53 MB). Plain phase-1 loads (VGPR 64 = occupancy granule;
// prefetch variant at 84 VGPR halved resident waves and regressed).
// Phase 1: K[264s][32e], V[32ch][264s] in LDS from corrT tile x W_kv (L1-hot);
// bf16 packing via v_cvt_pk_bf16_f32 (VALU trim vs scalar f2bf).
// Phase 2: QK^T, bias, softmax, in-reg P transpose, PV.
// LDS: K at [0,17408) = [272 s][32 e]; V at [17408,35840) = [9 kk][32 ch][32 s].
// Swizzle: 16B-slot sl within each 256B macro-row stored at sl ^ (mr&15).
__global__ __launch_bounds__(320, 3) void attn_kernel(
    const unsigned short* __restrict__ corrT, // [b][NPAD][128]
    const unsigned short* __restrict__ wkv,   // [512][128] bf16: rows 0..255 Wk, 256..511 Wv
    const float* __restrict__ bkv,            // [512] fp32 bias: K then V
    const unsigned short* __restrict__ qpT,   // [b][NPIX][256]
    const float* __restrict__ bias272,        // [b][272] additive mask bias
    unsigned short* __restrict__ attT)        // [b][NPIX][256]
{
    int lin = blockIdx.y * 8 + blockIdx.x;
    int xcd = lin & 7, idx = lin >> 3;
    int q = (xcd << 5) | (idx & 31);
    int g = idx >> 5;
    int b = blockIdx.z;
    int t = threadIdx.x;
    int w = t >> 6, lane = t & 63;
    int lm = lane & 15, lg = lane >> 4;

    __shared__ __align__(16) unsigned short sbuf[17920];   // 35840 B: K then V
    const int VB = 8704;                                    // V base in shorts

    // Q frag (B operand: lane holds Q[d=16w+lm][e=g*32+lg*8+j]); clamp + zero d>=65
    int d = w * 16 + lm;
    int dc = d < 64 ? d : 64;
    bf16x8 qa = *(const bf16x8*)&qpT[((size_t)b * NPIX + q * 65 + dc) * 256 + g * 32 + lg * 8];
    if (d >= TD) { bf16x8 z = {}; qa = z; }

    // ---- phase 1: in-block K/V projection (plain loads) ----
    bf16x8 wkf[2][4], wvf[2][4];
    #pragma unroll
    for (int et = 0; et < 2; et++)
        #pragma unroll
        for (int ks = 0; ks < 4; ks++) {
            wkf[et][ks] = *(const bf16x8*)&wkv[(size_t)(g * 32 + et * 16 + lm) * 128 + ks * 32 + lg * 8];
            wvf[et][ks] = *(const bf16x8*)&wkv[(size_t)(256 + g * 32 + et * 16 + lm) * 128 + ks * 32 + lg * 8];
        }
    float bk_[2][4], bv_[2];
    #pragma unroll
    for (int et = 0; et < 2; et++) {
        #pragma unroll
        for (int r = 0; r < 4; r++) bk_[et][r] = bkv[g * 32 + et * 16 + lg * 4 + r];
        bv_[et] = bkv[256 + g * 32 + et * 16 + lm];
    }

    const unsigned short* cbase = corrT + ((size_t)b * NPAD + (size_t)q * 264) * 128;
    f32x4 zero4 = {0.f, 0.f, 0.f, 0.f};

    for (int sti = w; sti < 17; sti += 5) {
        int srow = sti * 16 + lm; if (srow > 263) srow = 263;   // pad rows are zeroed
        bf16x8 ct[4];
        #pragma unroll
        for (int ks = 0; ks < 4; ks++)
            ct[ks] = *(const bf16x8*)&cbase[(size_t)srow * 128 + ks * 32 + lg * 8];
        f32x4 ak0 = zero4, ak1 = zero4, av0 = zero4, av1 = zero4;
        #pragma unroll
        for (int ks = 0; ks < 4; ks++) {
            ak0 = __builtin_amdgcn_mfma_f32_16x16x32_bf16(wkf[0][ks], ct[ks], ak0, 0, 0, 0);
            ak1 = __builtin_amdgcn_mfma_f32_16x16x32_bf16(wkf[1][ks], ct[ks], ak1, 0, 0, 0);
            av0 = __builtin_amdgcn_mfma_f32_16x16x32_bf16(ct[ks], wvf[0][ks], av0, 0, 0, 0);
            av1 = __builtin_amdgcn_mfma_f32_16x16x32_bf16(ct[ks], wvf[1][ks], av1, 0, 0, 0);
        }
        // K writes: lane holds K[e=et*16+lg*4+r][s=sti*16+lm]
        {
            int s = sti * 16 + lm;
            #pragma unroll
            for (int et = 0; et < 2; et++) {
                unsigned u = (unsigned)(s * 64 + et * 32 + lg * 8);
                unsigned mr = u >> 8, sl = (u >> 4) & 15;
                unsigned us = (u & ~0xF0u) | ((sl ^ (mr & 15)) << 4);
                f32x4 a = et ? ak1 : ak0;
                float v0 = a[0] + bk_[et][0], v1 = a[1] + bk_[et][1];
                float v2 = a[2] + bk_[et][2], v3 = a[3] + bk_[et][3];
                uint2 pk;
                asm("v_cvt_pk_bf16_f32 %0, %1, %2" : "=v"(pk.x) : "v"(v0), "v"(v1));
                asm("v_cvt_pk_bf16_f32 %0, %1, %2" : "=v"(pk.y) : "v"(v2), "v"(v3));
                *(uint2*)((char*)sbuf + us) = pk;
            }
        }
        // V writes: lane holds V[ch=et*16+lm][s=sti*16+lg*4+r]
        {
            int s0 = sti * 16 + lg * 4;
            unsigned vb_off = (unsigned)((s0 >> 5) * 2048 + (s0 & 31) * 2);
            #pragma unroll
            for (int et = 0; et < 2; et++) {
                int ch = et * 16 + lm;
                unsigned ov = vb_off + (unsigned)ch * 64u;
                unsigned mr = ov >> 8, sl = (ov >> 4) & 15;
                unsigned ovs = (ov & ~0xF0u) | ((sl ^ (mr & 15)) << 4);
                f32x4 a = et ? av1 : av0;
                float v0 = a[0] + bv_[et], v1 = a[1] + bv_[et];
                float v2 = a[2] + bv_[et], v3 = a[3] + bv_[et];
                uint2 pk;
                asm("v_cvt_pk_bf16_f32 %0, %1, %2" : "=v"(pk.x) : "v"(v0), "v"(v1));
                asm("v_cvt_pk_bf16_f32 %0, %1, %2" : "=v"(pk.y) : "v"(v2), "v"(v3));
                *(uint2*)((char*)sbuf + 17408 + ovs) = pk;
            }
        }
    }
    // zero-fill V window s in [272,288)
    if (t < 128) {
        int ch = t >> 2, j = t & 3;
        unsigned ov = 16384u + (unsigned)ch * 64u + 32u + (unsigned)j * 8u;
        unsigned mr = ov >> 8, sl = (ov >> 4) & 15;
        unsigned ovs = (ov & ~0xF0u) | ((sl ^ (mr & 15)) << 4);
        uint2 z2; z2.x = 0u; z2.y = 0u;
        *(uint2*)((char*)sbuf + 17408 + ovs) = z2;
    }
    __syncthreads();

    // ---- phase 2: QK^T from LDS: c[tt] holds S^T[s=16tt+4lg+r][d=lm] ----
    f32x4 c[17];
    int sl0 = ((lm & 3) << 2) | lg;
    #pragma unroll
    for (int tt = 0; tt < 17; tt++) {
        int mr = tt * 4 + (lm >> 2);
        bf16x8 kf = *(const bf16x8*)&sbuf[mr * 128 + ((sl0 ^ (mr & 15)) << 3)];
        c[tt] = __builtin_amdgcn_mfma_f32_16x16x32_bf16(kf, qa, zero4, 0, 0, 0);
    }

    // additive mask bias: one aligned float4 per tile
    const float* bp = bias272 + b * 272 + lg * 4;
    #pragma unroll
    for (int tt = 0; tt < 17; tt++) {
        f32x4 bf = *(const f32x4*)&bp[tt * 16];
        c[tt][0] += bf[0]; c[tt][1] += bf[1]; c[tt][2] += bf[2]; c[tt][3] += bf[3];
    }

    // softmax: row d=lm lane-local over regs; reduce across lg via 2 shfls
    f32x4 mv = c[0];
    #pragma unroll
    for (int tt = 1; tt < 17; tt++) {
        mv[0] = fmaxf(mv[0], c[tt][0]); mv[1] = fmaxf(mv[1], c[tt][1]);
        mv[2] = fmaxf(mv[2], c[tt][2]); mv[3] = fmaxf(mv[3], c[tt][3]);
    }
    float mx = fmaxf(fmaxf(mv[0], mv[1]), fmaxf(mv[2], mv[3]));
    mx = fmaxf(mx, __shfl_xor(mx, 16));
    mx = fmaxf(mx, __shfl_xor(mx, 32));
    float sm = 0.f;
    #pragma unroll
    for (int tt = 0; tt < 17; tt++) {
        #pragma unroll
        for (int r = 0; r < 4; r++) { float e_ = __expf(c[tt][r] - mx); c[tt][r] = e_; sm += e_; }
    }
    sm += __shfl_xor(sm, 16);
    sm += __shfl_xor(sm, 32);
    float inv = 1.0f / sm;   // uniform across lg for fixed lm; applied at epilogue

    // pack P (unnormalized) to bf16 pairs
    unsigned plo[17], phi[17];
    #pragma unroll
    for (int tt = 0; tt < 17; tt++) {
        asm("v_cvt_pk_bf16_f32 %0, %1, %2" : "=v"(plo[tt]) : "v"(c[tt][0]), "v"(c[tt][1]));
        asm("v_cvt_pk_bf16_f32 %0, %1, %2" : "=v"(phi[tt]) : "v"(c[tt][2]), "v"(c[tt][3]));
    }

    // PV: in-register transpose (permlane32_swap + shfl_xor16) + V from LDS
    bool lgEven = (lane & 16) == 0;
    f32x4 o0 = zero4, o1 = zero4;
    #pragma unroll
    for (int kk = 0; kk < 9; kk++) {
        unsigned A = plo[2 * kk];
        unsigned C = phi[2 * kk];
        unsigned B = (2 * kk + 1 < 17) ? plo[2 * kk + 1] : 0u;
        unsigned D = (2 * kk + 1 < 17) ? phi[2 * kk + 1] : 0u;
        asm("v_permlane32_swap_b32 %0, %1" : "+v"(A), "+v"(B));
        asm("v_permlane32_swap_b32 %0, %1" : "+v"(C), "+v"(D));
        unsigned Ax = __shfl_xor(A, 16), Bx = __shfl_xor(B, 16);
        unsigned Cx = __shfl_xor(C, 16), Dx = __shfl_xor(D, 16);
        union { unsigned u[4]; bf16x8 v; } pa;
        pa.u[0] = lgEven ? A  : Bx;
        pa.u[1] = lgEven ? C  : Dx;
        pa.u[2] = lgEven ? Ax : B;
        pa.u[3] = lgEven ? Cx : D;
        int mr0 = kk * 8 + (lm >> 2), mr1 = mr0 + 4;
        bf16x8 v0 = *(const bf16x8*)&sbuf[VB + mr0 * 128 + ((sl0 ^ (mr0 & 15)) << 3)];
        bf16x8 v1 = *(const bf16x8*)&sbuf[VB + mr1 * 128 + ((sl0 ^ (mr1 & 15)) << 3)];
        o0 = __builtin_amdgcn_mfma_f32_16x16x32_bf16(pa.v, v0, o0, 0, 0, 0);
        o1 = __builtin_amdgcn_mfma_f32_16x16x32_bf16(pa.v, v1, o1, 0, 0, 0);
    }
    // epilogue: apply 1/sum (gather per-row inv) and store
    float invr[4];
    #pragma unroll
    for (int r = 0; r < 4; r++) invr[r] = __shfl(inv, lg * 4 + r);
    #pragma unroll
    for (int r = 0; r < 4; r++) {
        int dd = w * 16 + lg * 4 + r;
        if (dd < TD) {
            size_t nn = (size_t)b * NPIX + q * 65 + dd;
            attT[nn * 256 + g * 32 + lm]      = f2bf(o0[r] * invr[r]);
            attT[nn * 256 + g * 32 + 16 + lm] = f2bf(o1[r] * invr[r]);
        }
    }
}

// ---------------- stats over bf16 attT ----------------
__global__ void stats1_kernel(const unsigned short* __restrict__ attT, float* __restrict__ st) {
    int b = blockIdx.y;
    int t = threadIdx.x;
    int e8 = t & 31, g = e8 >> 3;
    int lane = t & 63;
    float s = 0.f, ss = 0.f;
    for (int r = blockIdx.x * 8 + (t >> 5); r < NPIX; r += gridDim.x * 8) {
        union { uint4 v; unsigned short us[8]; } u;
        u.v = *(const uint4*)&attT[((size_t)b * NPIX + r) * 256 + e8 * 8];
        #pragma unroll
        for (int j = 0; j < 8; j++) { float x = bf2f(u.us[j]); s += x; ss += x * x; }
    }
    s += __shfl_down(s, 32); ss += __shfl_down(ss, 32);
    s += __shfl_down(s, 4);  ss += __shfl_down(ss, 4);
    s += __shfl_down(s, 2);  ss += __shfl_down(ss, 2);
    s += __shfl_down(s, 1);  ss += __shfl_down(ss, 1);
    if (lane < 32 && (lane & 7) == 0) {
        atomicAdd(&st[(b * 4 + g) * 2],     s);
        atomicAdd(&st[(b * 4 + g) * 2 + 1], ss);
    }
}

// ---------------- z = relu(gn2(agg)) + relu(gn_sc(scr)), span-based, fused st3 ----
// grid (256, 16): blockIdx.y = span = b*4+cg, a contiguous 128xNPIX fp32 region.
// gn params are block-uniform (hoisted); st3 stats accumulated inline (saves a
// full 136MB re-read pass).
__global__ void z_kernel(float* __restrict__ out, const float* __restrict__ scr,
                         const float* __restrict__ st2, const float* __restrict__ stsc,
                         const float* __restrict__ g2w, const float* __restrict__ g2b,
                         const float* __restrict__ gsw, const float* __restrict__ gsb,
                         float* __restrict__ st3)
{
    const float invcnt = 1.0f / (128.0f * NPIX);
    int span = blockIdx.y;
    int cg = span & 3;
    float2 p2 = gn_params(st2,  span, invcnt);
    float2 ps = gn_params(stsc, span, invcnt);
    size_t base = (size_t)span * (128 * (size_t)NPIX);
    float4* o4 = reinterpret_cast<float4*>(out + base);
    const float4* s4 = reinterpret_cast<const float4*>(scr + base);
    const size_t len4 = (128 * (size_t)NPIX) >> 2;
    float s = 0.f, ss = 0.f;
    for (size_t i = (size_t)blockIdx.x * blockDim.x + threadIdx.x; i < len4;
         i += (size_t)gridDim.x * blockDim.x) {
        int c = cg * 128 + (int)((i * 4) / NPIX);
        float w2 = g2w[c] * p2.y, b2 = g2b[c] - p2.x * p2.y * g2w[c];
        float wsc = gsw[c] * ps.y, bsc = gsb[c] - ps.x * ps.y * gsw[c];
        float4 a = o4[i], r = s4[i], z;
        z.x = fmaxf(a.x * w2 + b2, 0.f) + fmaxf(r.x * wsc + bsc, 0.f);
        z.y = fmaxf(a.y * w2 + b2, 0.f) + fmaxf(r.y * wsc + bsc, 0.f);
        z.z = fmaxf(a.z * w2 + b2, 0.f) + fmaxf(r.z * wsc + bsc, 0.f);
        z.w = fmaxf(a.w * w2 + b2, 0.f) + fmaxf(r.w * wsc + bsc, 0.f);
        o4[i] = z;
        s  += z.x + z.y + z.z + z.w;
        ss += z.x * z.x + z.y * z.y + z.z * z.z + z.w * z.w;
    }
    #pragma unroll
    for (int o = 32; o > 0; o >>= 1) { s += __shfl_down(s, o, 64); ss += __shfl_down(ss, o, 64); }
    __shared__ float red[4][2];
    int wid = threadIdx.x >> 6, lane = threadIdx.x & 63;
    if (lane == 0) { red[wid][0] = s; red[wid][1] = ss; }
    __syncthreads();
    if (threadIdx.x == 0) {
        float S  = red[0][0] + red[1][0] + red[2][0] + red[3][0];
        float SS = red[0][1] + red[1][1] + red[2][1] + red[3][1];
        atomicAdd(&st3[span * 2],     S);
        atomicAdd(&st3[span * 2 + 1], SS);
    }
}

// ---------------- final gn_out, span-based (hoisted params) ----------------
__global__ void norm_kernel(float* __restrict__ out, const float* __restrict__ st3,
                            const float* __restrict__ gw, const float* __restrict__ gb)
{
    const float invcnt = 1.0f / (128.0f * NPIX);
    int span = blockIdx.y;
    int cg = span & 3;
    float2 p = gn_params(st3, span, invcnt);
    size_t base = (size_t)span * (128 * (size_t)NPIX);
    float4* o4 = reinterpret_cast<float4*>(out + base);
    const size_t len4 = (128 * (size_t)NPIX) >> 2;
    for (size_t i = (size_t)blockIdx.x * blockDim.x + threadIdx.x; i < len4;
         i += (size_t)gridDim.x * blockDim.x) {
        int c = cg * 128 + (int)((i * 4) / NPIX);
        float w_ = gw[c] * p.y, b_ = gb[c] - p.x * p.y * gw[c];
        float4 a = o4[i], z;
        z.x = a.x * w_ + b_; z.y = a.y * w_ + b_; z.z = a.z * w_ + b_; z.w = a.w * w_ + b_;
        o4[i] = z;
    }
}

extern "C" void kernel_launch(void* const* d_in, const int* in_sizes, int n_in,
                              void* d_out, int out_size, void* d_ws, size_t ws_size,
                              hipStream_t stream) {
    (void)in_sizes; (void)n_in; (void)out_size; (void)ws_size;
    const float* corr     = (const float*)d_in[0];
    const int*   smask    = (const int*)  d_in[1];
    const float* W_sc     = (const float*)d_in[2];
    const float* gn_sc_w  = (const float*)d_in[3];
    const float* gn_sc_b  = (const float*)d_in[4];
    const float* W_qkv    = (const float*)d_in[5];
    const float* b_qkv    = (const float*)d_in[6];
    const float* gn1_w    = (const float*)d_in[7];
    const float* gn1_b    = (const float*)d_in[8];
    const float* W_agg    = (const float*)d_in[9];
    const float* gn2_w    = (const float*)d_in[10];
    const float* gn2_b    = (const float*)d_in[11];
    const float* gn_out_w = (const float*)d_in[12];
    const float* gn_out_b = (const float*)d_in[13];
    float* out = (float*)d_out;

    unsigned short* ws = (unsigned short*)d_ws;
    unsigned short* corrT  = ws;                           // 34,603,008 sh
    unsigned short* kbuf   = corrT  + (size_t)34603008;    // (dead space, kept for layout)
    unsigned short* vbuf   = kbuf   + (size_t)69206016;    // (dead space, kept for layout)
    unsigned short* corrpT = vbuf   + (size_t)69206016;    //  8,519,680 sh
    unsigned short* qpT    = corrpT + (size_t)8519680;     // 17,039,360 sh
    unsigned short* attT   = qpT    + (size_t)17039360;    // 17,039,360 sh
    unsigned short* wbuf   = attT   + (size_t)17039360;    //    294,912 sh
    float* bias  = (float*)(wbuf + (size_t)294912);        // 1,088 f  ([b][272])
    float* stats = bias + 1088;                            // 128 f
    float* scr   = (float*)d_ws;   // aliases corrT+kbuf head (dead by SC gemm)
    float* st_sc = stats, *st1 = stats + 32, *st2 = stats + 64, *st3 = stats + 96;
    (void)kbuf; (void)vbuf;

    const float inv1 = 1.0f / (64.0f * (float)NPIX);

    hipMemsetAsync(stats, 0, 128 * sizeof(float), stream);
    wprep_kernel<<<dim3(1152), dim3(256), 0, stream>>>(W_qkv, W_sc, W_agg, wbuf);
    mask_kernel<<<dim3(NB), dim3(320), 0, stream>>>(smask, bias);
    tpool_kernel<<<dim3(TQ, 2, NB), dim3(256), 0, stream>>>(corr, corrT, corrpT);
    // Q projection: qpT[b][n][256] = Wq x corrpT + bq
    mgemm_kernel<0,128><<<dim3(130, 2, NB), dim3(256), 0, stream>>>(
        corrpT, wbuf, NPIX, nullptr, qpT, b_qkv,
        nullptr, nullptr, nullptr, 0.f, nullptr);
    // fused KV projection + attention (XCD-local (g,q) remap inside)
    attn_kernel<<<dim3(8, TQ, NB), dim3(320), 0, stream>>>(
        corrT, wbuf + 32768, b_qkv + 256, qpT, bias, attT);
    stats1_kernel<<<dim3(208, NB), dim3(256), 0, stream>>>(attT, st1);
    // agg conv with fused gn1+relu on input and fused st2 accumulation
    mgemm_kernel<3,256><<<dim3(130, 4, NB), dim3(256), 0, stream>>>(
        attT, wbuf + 163840, NPIX, out, nullptr, nullptr,
        st1, gn1_w, gn1_b, inv1, st2);
    // residual conv with fused st_sc accumulation
    mgemm_kernel<2,128><<<dim3(130, 4, NB), dim3(256), 0, stream>>>(
        corrpT, wbuf + 98304, NPIX, scr, nullptr, nullptr,
        nullptr, nullptr, nullptr, 0.f, st_sc);
    // z + fused st3 accumulation (span-based)
    z_kernel<<<dim3(256, 16), dim3(256), 0, stream>>>(
        out, scr, st2, st_sc, gn2_w, gn2_b, gn_sc_w, gn_sc_b, st3);
    norm_kernel<<<dim3(256, 16), dim3(256), 0, stream>>>(out, st3, gn_out_w, gn_out_b);
}

// Round 8
// 896.153 us; speedup vs baseline: 1.1156x; 1.0496x over previous
//
#include <hip/hip_runtime.h>
#include <stdint.h>

#define NB    4
#define TQ    256
#define TS    257
#define TD    65
#define NPIX  16640        /* TQ*TD */
#define NPADQ 264          /* padded s per q */
#define NPAD  67584        /* 256*264 */
#define COUT  512
#define HID   256

typedef __attribute__((ext_vector_type(8))) short bf16x8;
typedef __attribute__((ext_vector_type(4))) float f32x4;

// ---------------- bf16 helpers ----------------
__device__ __forceinline__ float bf2f(unsigned short u) {
    union { unsigned int i; float f; } v; v.i = ((unsigned int)u) << 16; return v.f;
}
__device__ __forceinline__ unsigned short f2bf(float x) {
    union { float f; unsigned int i; } v; v.f = x;
    unsigned int r = v.i + 0x7fffu + ((v.i >> 16) & 1u);
    return (unsigned short)(r >> 16);
}

__device__ __forceinline__ float2 gn_params(const float* st, int bg, float invcnt) {
    float mu  = st[bg * 2] * invcnt;
    float var = st[bg * 2 + 1] * invcnt - mu * mu;
    float2 r; r.x = mu; r.y = rsqrtf(var + 1e-5f); return r;
}

// ---------------- weight cast fp32 -> bf16 ----------------
__global__ void wprep_kernel(const float* __restrict__ wq, const float* __restrict__ wsc,
                             const float* __restrict__ wagg, unsigned short* __restrict__ wb) {
    int i = blockIdx.x * 256 + threadIdx.x;   // grid 1152 -> 294912
    float v;
    if (i < 98304) v = wq[i];
    else if (i < 163840) v = wsc[i - 98304];
    else v = wagg[i - 163840];
    wb[i] = f2bf(v);
}

// ---------------- mask: additive bias table [b][272] (0 or -1e9) ----------------
__global__ void mask_kernel(const int* __restrict__ sm, float* __restrict__ bias) {
    int b = blockIdx.x; int t = threadIdx.x;   // 320 threads
    if (t >= 272) return;
    float v;
    if (t == 0) v = 0.0f;
    else if (t <= 256) {
        int s = t - 1; int i = s >> 4, j = s & 15;
        v = (sm[(size_t)b * 65536 + i * 17 * 256 + j * 17] != 0) ? 0.0f : -1e9f;
    } else v = -1e9f;
    bias[b * 272 + t] = v;
}

// ---------------- fused transpose + pool ----------------
__global__ __launch_bounds__(256) void tpool_kernel(
    const float* __restrict__ corr,
    unsigned short* __restrict__ corrT,    // [b][NPAD][128]
    unsigned short* __restrict__ corrpT)   // [b][NPIX][128]
{
    int q = blockIdx.x, ch = blockIdx.y, b = blockIdx.z;
    int t = threadIdx.x;
    __shared__ unsigned short sT[264 * 66];

    {
        int laneT = t & 63; int crow = t >> 6;
        for (int c = crow; c < 64; c += 4) {
            const float* src = corr + (((size_t)b * 128 + ch * 64 + c) * 256 + q) * 257;
            for (int s = laneT; s < 257; s += 64) sT[s * 66 + c] = f2bf(src[s]);
        }
    }
    for (int idx = t; idx < 7 * 66; idx += 256) {
        int s = 257 + idx / 66, c = idx % 66;
        sT[s * 66 + c] = 0;
    }
    __syncthreads();

    {
        unsigned int* dst = (unsigned int*)corrT;
        size_t base = (size_t)b * (NPAD * 64) + (size_t)q * (264 * 64) + ch * 32;
        for (int idx = t; idx < 264 * 32; idx += 256) {
            int s = idx >> 5, cu = idx & 31;
            unsigned int v = (unsigned int)sT[s * 66 + 2 * cu] |
                             ((unsigned int)sT[s * 66 + 2 * cu + 1] << 16);
            dst[base + (size_t)s * 64 + cu] = v;
        }
    }
    {
        unsigned int* dst = (unsigned int*)corrpT;
        size_t base = (size_t)b * (NPIX * 64) + (size_t)q * (65 * 64) + ch * 32;
        for (int idx = t; idx < 65 * 32; idx += 256) {
            int d = idx >> 5, cu = idx & 31;
            float x0, x1;
            if (d == 0) {
                x0 = bf2f(sT[0 * 66 + 2 * cu]); x1 = bf2f(sT[0 * 66 + 2 * cu + 1]);
            } else {
                int dd = d - 1; int i = dd >> 3, j = dd & 7;
                int s = 1 + i * 32 + j * 2;
                int c0 = 2 * cu, c1 = 2 * cu + 1;
                x0 = 0.25f * (bf2f(sT[s*66+c0]) + bf2f(sT[(s+1)*66+c0]) +
                              bf2f(sT[(s+16)*66+c0]) + bf2f(sT[(s+17)*66+c0]));
                x1 = 0.25f * (bf2f(sT[s*66+c1]) + bf2f(sT[(s+1)*66+c1]) +
                              bf2f(sT[(s+16)*66+c1]) + bf2f(sT[(s+17)*66+c1]));
            }
            unsigned int v = (unsigned int)f2bf(x0) | ((unsigned int)f2bf(x1) << 16);
            dst[base + (size_t)d * 64 + cu] = v;
        }
    }
}

// ---------------- unified MFMA GEMM (modes 0,2,3 used) ----------------
// MODE 0: bf16 out [b][n][256] (+bias). MODE 2/3: bf16 out [b][COUT][NPIX] (uint2 of
// 4 consecutive n) + fused GroupNorm stats of own output (fp32 pre-round) -> 2 atomics
// per block (an m-block of 128 rows is one group: bg = b*4 + blockIdx.y).
template<int MODE, int KT>
__global__ __launch_bounds__(256) void mgemm_kernel(
    const unsigned short* __restrict__ X,
    const unsigned short* __restrict__ Wb,
    int Nn,
    unsigned short* __restrict__ Y16,
    const float* __restrict__ bias,
    const float* __restrict__ st, const float* __restrict__ gw, const float* __restrict__ gb,
    float invcnt,
    float* __restrict__ stacc)
{
    int b  = blockIdx.z;
    int n0 = blockIdx.x * 128;
    int m0 = blockIdx.y * 128;
    int t = threadIdx.x;
    int w = t >> 6, lane = t & 63;
    int lm = lane & 15, lg = lane >> 4;
    int wn = (w & 1) * 64, wm = (w >> 1) * 64;

    __shared__ __align__(16) unsigned short sX[16384];
    __shared__ __align__(16) unsigned short sW[16384];
    __shared__ float red2[4][2];

    f32x4 acc[4][4];
    #pragma unroll
    for (int i = 0; i < 4; i++)
        #pragma unroll
        for (int j = 0; j < 4; j++) { acc[i][j][0]=0.f; acc[i][j][1]=0.f; acc[i][j][2]=0.f; acc[i][j][3]=0.f; }

    for (int kc = 0; kc < KT / 128; kc++) {
        for (int i = t; i < 2048; i += 256) {
            int r_ = i >> 4, kq = i & 15;
            uint4 xv = *(const uint4*)&X[((size_t)b * Nn + n0 + r_) * KT + kc * 128 + (kq << 3)];
            if (MODE == 3) {
                union { uint4 v; unsigned short us[8]; } u; u.v = xv;
                int c0 = kc * 128 + (kq << 3);
                float2 p = gn_params(st, b * 4 + (c0 >> 6), invcnt);
                #pragma unroll
                for (int jj = 0; jj < 8; jj++) {
                    int cc = c0 + jj;
                    float v = bf2f(u.us[jj]);
                    v = fmaxf((v - p.x) * p.y * gw[cc] + gb[cc], 0.0f);
                    u.us[jj] = f2bf(v);
                }
                xv = u.v;
            }
            *(uint4*)&sX[r_ * 128 + ((kq ^ (r_ & 15)) << 3)] = xv;
            uint4 wv = *(const uint4*)&Wb[((size_t)(m0 + r_)) * KT + kc * 128 + (kq << 3)];
            *(uint4*)&sW[r_ * 128 + ((kq ^ (r_ & 15)) << 3)] = wv;
        }
        __syncthreads();
        #pragma unroll
        for (int kk = 0; kk < 4; kk++) {
            int kg = (kk << 2) | lg;
            bf16x8 af[4], bw[4];
            #pragma unroll
            for (int ii = 0; ii < 4; ii++)
                af[ii] = *(const bf16x8*)&sX[(wn + ii * 16 + lm) * 128 + ((kg ^ lm) << 3)];
            #pragma unroll
            for (int jj = 0; jj < 4; jj++)
                bw[jj] = *(const bf16x8*)&sW[(wm + jj * 16 + lm) * 128 + ((kg ^ lm) << 3)];
            #pragma unroll
            for (int ii = 0; ii < 4; ii++)
                #pragma unroll
                for (int jj = 0; jj < 4; jj++) {
                    if (MODE == 0)
                        acc[ii][jj] = __builtin_amdgcn_mfma_f32_16x16x32_bf16(bw[jj], af[ii], acc[ii][jj], 0,0,0);
                    else
                        acc[ii][jj] = __builtin_amdgcn_mfma_f32_16x16x32_bf16(af[ii], bw[jj], acc[ii][jj], 0,0,0);
                }
        }
        __syncthreads();
    }

    if (MODE == 0) {
        #pragma unroll
        for (int ii = 0; ii < 4; ii++) {
            int n = n0 + wn + ii * 16 + lm;
            #pragma unroll
            for (int jj = 0; jj < 4; jj++) {
                int mb = m0 + wm + jj * 16 + lg * 4;
                union { unsigned short us[4]; uint2 v; } pk;
                #pragma unroll
                for (int r = 0; r < 4; r++) pk.us[r] = f2bf(acc[ii][jj][r] + bias[mb + r]);
                *(uint2*)&Y16[((size_t)b * NPIX + n) * 256 + mb] = pk.v;
            }
        }
    } else {
        float s = 0.f, ss = 0.f;
        #pragma unroll
        for (int ii = 0; ii < 4; ii++) {
            int nb = n0 + wn + ii * 16 + lg * 4;
            #pragma unroll
            for (int jj = 0; jj < 4; jj++) {
                int m = m0 + wm + jj * 16 + lm;
                f32x4 a = acc[ii][jj];
                uint2 pk;
                asm("v_cvt_pk_bf16_f32 %0, %1, %2" : "=v"(pk.x) : "v"(a[0]), "v"(a[1]));
                asm("v_cvt_pk_bf16_f32 %0, %1, %2" : "=v"(pk.y) : "v"(a[2]), "v"(a[3]));
                *(uint2*)&Y16[((size_t)b * COUT + m) * NPIX + nb] = pk;
                #pragma unroll
                for (int r = 0; r < 4; r++) { float v = a[r]; s += v; ss += v * v; }
            }
        }
        // block stat reduce (whole block is one (b, group))
        #pragma unroll
        for (int o = 32; o > 0; o >>= 1) { s += __shfl_down(s, o, 64); ss += __shfl_down(ss, o, 64); }
        if (lane == 0) { red2[w][0] = s; red2[w][1] = ss; }
        __syncthreads();
        if (t == 0) {
            float S  = red2[0][0] + red2[1][0] + red2[2][0] + red2[3][0];
            float SS = red2[0][1] + red2[1][1] + red2[2][1] + red2[3][1];
            int bg = b * 4 + blockIdx.y;
            atomicAdd(&stacc[bg * 2],     S);
            atomicAdd(&stacc[bg * 2 + 1], SS);
        }
    }
}

// ---------------- fused KV-projection + MFMA attention (+ fused gn1 stats) ----------
// grid (8, 256, 4); 320 threads = 5 waves. (g,q) REMAPPED so all 8 g-blocks sharing a
// corrT q-tile land on the SAME XCD (verified: FETCH 303 MB -> 53 MB). Plain phase-1
// loads (VGPR 64 = occupancy granule). bf16 packing via v_cvt_pk_bf16_f32.
// Epilogue also accumulates gn1 stats of the normalized outputs (block channels
// g*32..g*32+31 lie within gn1 group g>>1) -> removes the separate stats1 pass.
// LDS: K at [0,17408) = [272 s][32 e]; V at [17408,35840) = [9 kk][32 ch][32 s].
// Swizzle: 16B-slot sl within each 256B macro-row stored at sl ^ (mr&15).
__global__ __launch_bounds__(320, 3) void attn_kernel(
    const unsigned short* __restrict__ corrT, // [b][NPAD][128]
    const unsigned short* __restrict__ wkv,   // [512][128] bf16: rows 0..255 Wk, 256..511 Wv
    const float* __restrict__ bkv,            // [512] fp32 bias: K then V
    const unsigned short* __restrict__ qpT,   // [b][NPIX][256]
    const float* __restrict__ bias272,        // [b][272] additive mask bias
    unsigned short* __restrict__ attT,        // [b][NPIX][256]
    float* __restrict__ st1)                  // [16*2] gn1 stats accumulator
{
    int lin = blockIdx.y * 8 + blockIdx.x;
    int xcd = lin & 7, idx = lin >> 3;
    int q = (xcd << 5) | (idx & 31);
    int g = idx >> 5;
    int b = blockIdx.z;
    int t = threadIdx.x;
    int w = t >> 6, lane = t & 63;
    int lm = lane & 15, lg = lane >> 4;

    __shared__ __align__(16) unsigned short sbuf[17920];   // 35840 B: K then V
    __shared__ float sred[5][2];
    const int VB = 8704;                                    // V base in shorts

    // Q frag (B operand: lane holds Q[d=16w+lm][e=g*32+lg*8+j]); clamp + zero d>=65
    int d = w * 16 + lm;
    int dc = d < 64 ? d : 64;
    bf16x8 qa = *(const bf16x8*)&qpT[((size_t)b * NPIX + q * 65 + dc) * 256 + g * 32 + lg * 8];
    if (d >= TD) { bf16x8 z = {}; qa = z; }

    // ---- phase 1: in-block K/V projection (plain loads) ----
    bf16x8 wkf[2][4], wvf[2][4];
    #pragma unroll
    for (int et = 0; et < 2; et++)
        #pragma unroll
        for (int ks = 0; ks < 4; ks++) {
            wkf[et][ks] = *(const bf16x8*)&wkv[(size_t)(g * 32 + et * 16 + lm) * 128 + ks * 32 + lg * 8];
            wvf[et][ks] = *(const bf16x8*)&wkv[(size_t)(256 + g * 32 + et * 16 + lm) * 128 + ks * 32 + lg * 8];
        }
    float bk_[2][4], bv_[2];
    #pragma unroll
    for (int et = 0; et < 2; et++) {
        #pragma unroll
        for (int r = 0; r < 4; r++) bk_[et][r] = bkv[g * 32 + et * 16 + lg * 4 + r];
        bv_[et] = bkv[256 + g * 32 + et * 16 + lm];
    }

    const unsigned short* cbase = corrT + ((size_t)b * NPAD + (size_t)q * 264) * 128;
    f32x4 zero4 = {0.f, 0.f, 0.f, 0.f};

    for (int sti = w; sti < 17; sti += 5) {
        int srow = sti * 16 + lm; if (srow > 263) srow = 263;   // pad rows are zeroed
        bf16x8 ct[4];
        #pragma unroll
        for (int ks = 0; ks < 4; ks++)
            ct[ks] = *(const bf16x8*)&cbase[(size_t)srow * 128 + ks * 32 + lg * 8];
        f32x4 ak0 = zero4, ak1 = zero4, av0 = zero4, av1 = zero4;
        #pragma unroll
        for (int ks = 0; ks < 4; ks++) {
            ak0 = __builtin_amdgcn_mfma_f32_16x16x32_bf16(wkf[0][ks], ct[ks], ak0, 0, 0, 0);
            ak1 = __builtin_amdgcn_mfma_f32_16x16x32_bf16(wkf[1][ks], ct[ks], ak1, 0, 0, 0);
            av0 = __builtin_amdgcn_mfma_f32_16x16x32_bf16(ct[ks], wvf[0][ks], av0, 0, 0, 0);
            av1 = __builtin_amdgcn_mfma_f32_16x16x32_bf16(ct[ks], wvf[1][ks], av1, 0, 0, 0);
        }
        // K writes: lane holds K[e=et*16+lg*4+r][s=sti*16+lm]
        {
            int s = sti * 16 + lm;
            #pragma unroll
            for (int et = 0; et < 2; et++) {
                unsigned u = (unsigned)(s * 64 + et * 32 + lg * 8);
                unsigned mr = u >> 8, sl = (u >> 4) & 15;
                unsigned us = (u & ~0xF0u) | ((sl ^ (mr & 15)) << 4);
                f32x4 a = et ? ak1 : ak0;
                float v0 = a[0] + bk_[et][0], v1 = a[1] + bk_[et][1];
                float v2 = a[2] + bk_[et][2], v3 = a[3] + bk_[et][3];
                uint2 pk;
                asm("v_cvt_pk_bf16_f32 %0, %1, %2" : "=v"(pk.x) : "v"(v0), "v"(v1));
                asm("v_cvt_pk_bf16_f32 %0, %1, %2" : "=v"(pk.y) : "v"(v2), "v"(v3));
                *(uint2*)((char*)sbuf + us) = pk;
            }
        }
        // V writes: lane holds V[ch=et*16+lm][s=sti*16+lg*4+r]
        {
            int s0 = sti * 16 + lg * 4;
            unsigned vb_off = (unsigned)((s0 >> 5) * 2048 + (s0 & 31) * 2);
            #pragma unroll
            for (int et = 0; et < 2; et++) {
                int ch = et * 16 + lm;
                unsigned ov = vb_off + (unsigned)ch * 64u;
                unsigned mr = ov >> 8, sl = (ov >> 4) & 15;
                unsigned ovs = (ov & ~0xF0u) | ((sl ^ (mr & 15)) << 4);
                f32x4 a = et ? av1 : av0;
                float v0 = a[0] + bv_[et], v1 = a[1] + bv_[et];
                float v2 = a[2] + bv_[et], v3 = a[3] + bv_[et];
                uint2 pk;
                asm("v_cvt_pk_bf16_f32 %0, %1, %2" : "=v"(pk.x) : "v"(v0), "v"(v1));
                asm("v_cvt_pk_bf16_f32 %0, %1, %2" : "=v"(pk.y) : "v"(v2), "v"(v3));
                *(uint2*)((char*)sbuf + 17408 + ovs) = pk;
            }
        }
    }
    // zero-fill V window s in [272,288)
    if (t < 128) {
        int ch = t >> 2, j = t & 3;
        unsigned ov = 16384u + (unsigned)ch * 64u + 32u + (unsigned)j * 8u;
        unsigned mr = ov >> 8, sl = (ov >> 4) & 15;
        unsigned ovs = (ov & ~0xF0u) | ((sl ^ (mr & 15)) << 4);
        uint2 z2; z2.x = 0u; z2.y = 0u;
        *(uint2*)((char*)sbuf + 17408 + ovs) = z2;
    }
    __syncthreads();

    // ---- phase 2: QK^T from LDS: c[tt] holds S^T[s=16tt+4lg+r][d=lm] ----
    f32x4 c[17];
    int sl0 = ((lm & 3) << 2) | lg;
    #pragma unroll
    for (int tt = 0; tt < 17; tt++) {
        int mr = tt * 4 + (lm >> 2);
        bf16x8 kf = *(const bf16x8*)&sbuf[mr * 128 + ((sl0 ^ (mr & 15)) << 3)];
        c[tt] = __builtin_amdgcn_mfma_f32_16x16x32_bf16(kf, qa, zero4, 0, 0, 0);
    }

    // additive mask bias: one aligned float4 per tile
    const float* bp = bias272 + b * 272 + lg * 4;
    #pragma unroll
    for (int tt = 0; tt < 17; tt++) {
        f32x4 bf = *(const f32x4*)&bp[tt * 16];
        c[tt][0] += bf[0]; c[tt][1] += bf[1]; c[tt][2] += bf[2]; c[tt][3] += bf[3];
    }

    // softmax: row d=lm lane-local over regs; reduce across lg via 2 shfls
    f32x4 mv = c[0];
    #pragma unroll
    for (int tt = 1; tt < 17; tt++) {
        mv[0] = fmaxf(mv[0], c[tt][0]); mv[1] = fmaxf(mv[1], c[tt][1]);
        mv[2] = fmaxf(mv[2], c[tt][2]); mv[3] = fmaxf(mv[3], c[tt][3]);
    }
    float mx = fmaxf(fmaxf(mv[0], mv[1]), fmaxf(mv[2], mv[3]));
    mx = fmaxf(mx, __shfl_xor(mx, 16));
    mx = fmaxf(mx, __shfl_xor(mx, 32));
    float sm = 0.f;
    #pragma unroll
    for (int tt = 0; tt < 17; tt++) {
        #pragma unroll
        for (int r = 0; r < 4; r++) { float e_ = __expf(c[tt][r] - mx); c[tt][r] = e_; sm += e_; }
    }
    sm += __shfl_xor(sm, 16);
    sm += __shfl_xor(sm, 32);
    float inv = 1.0f / sm;   // uniform across lg for fixed lm; applied at epilogue

    // pack P (unnormalized) to bf16 pairs
    unsigned plo[17], phi[17];
    #pragma unroll
    for (int tt = 0; tt < 17; tt++) {
        asm("v_cvt_pk_bf16_f32 %0, %1, %2" : "=v"(plo[tt]) : "v"(c[tt][0]), "v"(c[tt][1]));
        asm("v_cvt_pk_bf16_f32 %0, %1, %2" : "=v"(phi[tt]) : "v"(c[tt][2]), "v"(c[tt][3]));
    }

    // PV: in-register transpose (permlane32_swap + shfl_xor16) + V from LDS
    bool lgEven = (lane & 16) == 0;
    f32x4 o0 = zero4, o1 = zero4;
    #pragma unroll
    for (int kk = 0; kk < 9; kk++) {
        unsigned A = plo[2 * kk];
        unsigned C = phi[2 * kk];
        unsigned B = (2 * kk + 1 < 17) ? plo[2 * kk + 1] : 0u;
        unsigned D = (2 * kk + 1 < 17) ? phi[2 * kk + 1] : 0u;
        asm("v_permlane32_swap_b32 %0, %1" : "+v"(A), "+v"(B));
        asm("v_permlane32_swap_b32 %0, %1" : "+v"(C), "+v"(D));
        unsigned Ax = __shfl_xor(A, 16), Bx = __shfl_xor(B, 16);
        unsigned Cx = __shfl_xor(C, 16), Dx = __shfl_xor(D, 16);
        union { unsigned u[4]; bf16x8 v; } pa;
        pa.u[0] = lgEven ? A  : Bx;
        pa.u[1] = lgEven ? C  : Dx;
        pa.u[2] = lgEven ? Ax : B;
        pa.u[3] = lgEven ? Cx : D;
        int mr0 = kk * 8 + (lm >> 2), mr1 = mr0 + 4;
        bf16x8 v0 = *(const bf16x8*)&sbuf[VB + mr0 * 128 + ((sl0 ^ (mr0 & 15)) << 3)];
        bf16x8 v1 = *(const bf16x8*)&sbuf[VB + mr1 * 128 + ((sl0 ^ (mr1 & 15)) << 3)];
        o0 = __builtin_amdgcn_mfma_f32_16x16x32_bf16(pa.v, v0, o0, 0, 0, 0);
        o1 = __builtin_amdgcn_mfma_f32_16x16x32_bf16(pa.v, v1, o1, 0, 0, 0);
    }
    // epilogue: apply 1/sum, store, and accumulate gn1 stats of stored values
    float invr[4];
    #pragma unroll
    for (int r = 0; r < 4; r++) invr[r] = __shfl(inv, lg * 4 + r);
    float s1 = 0.f, ss1 = 0.f;
    #pragma unroll
    for (int r = 0; r < 4; r++) {
        int dd = w * 16 + lg * 4 + r;
        if (dd < TD) {
            size_t nn = (size_t)b * NPIX + q * 65 + dd;
            float z0 = o0[r] * invr[r], z1 = o1[r] * invr[r];
            attT[nn * 256 + g * 32 + lm]      = f2bf(z0);
            attT[nn * 256 + g * 32 + 16 + lm] = f2bf(z1);
            s1 += z0 + z1; ss1 += z0 * z0 + z1 * z1;
        }
    }
    #pragma unroll
    for (int o = 32; o > 0; o >>= 1) { s1 += __shfl_down(s1, o, 64); ss1 += __shfl_down(ss1, o, 64); }
    if (lane == 0) { sred[w][0] = s1; sred[w][1] = ss1; }
    __syncthreads();
    if (t == 0) {
        float S  = sred[0][0] + sred[1][0] + sred[2][0] + sred[3][0] + sred[4][0];
        float SS = sred[0][1] + sred[1][1] + sred[2][1] + sred[3][1] + sred[4][1];
        int bg1 = b * 4 + (g >> 1);
        atomicAdd(&st1[bg1 * 2],     S);
        atomicAdd(&st1[bg1 * 2 + 1], SS);
    }
}

// ---------------- z = relu(gn2(aggb)) + relu(gn_sc(scrb)), bf16 in, fp32 out, fused st3 ----
// grid (256, 16): blockIdx.y = span = b*4+cg, a contiguous 128xNPIX region.
__global__ void z_kernel(float* __restrict__ out,
                         const unsigned short* __restrict__ aggb,
                         const unsigned short* __restrict__ scrb,
                         const float* __restrict__ st2, const float* __restrict__ stsc,
                         const float* __restrict__ g2w, const float* __restrict__ g2b,
                         const float* __restrict__ gsw, const float* __restrict__ gsb,
                         float* __restrict__ st3)
{
    const float invcnt = 1.0f / (128.0f * NPIX);
    int span = blockIdx.y;
    int cg = span & 3;
    float2 p2 = gn_params(st2,  span, invcnt);
    float2 ps = gn_params(stsc, span, invcnt);
    size_t base = (size_t)span * (128 * (size_t)NPIX);
    float4* o4 = reinterpret_cast<float4*>(out + base);
    const uint2* a2 = reinterpret_cast<const uint2*>(aggb + base);
    const uint2* s2 = reinterpret_cast<const uint2*>(scrb + base);
    const size_t len4 = (128 * (size_t)NPIX) >> 2;
    float s = 0.f, ss = 0.f;
    for (size_t i = (size_t)blockIdx.x * blockDim.x + threadIdx.x; i < len4;
         i += (size_t)gridDim.x * blockDim.x) {
        int c = cg * 128 + (int)((i * 4) / NPIX);
        float w2 = g2w[c] * p2.y, b2 = g2b[c] - p2.x * p2.y * g2w[c];
        float wsc = gsw[c] * ps.y, bsc = gsb[c] - ps.x * ps.y * gsw[c];
        uint2 av = a2[i], rv = s2[i];
        float ax = bf2f((unsigned short)(av.x & 0xffff)), ay = bf2f((unsigned short)(av.x >> 16));
        float az = bf2f((unsigned short)(av.y & 0xffff)), aw = bf2f((unsigned short)(av.y >> 16));
        float rx = bf2f((unsigned short)(rv.x & 0xffff)), ry = bf2f((unsigned short)(rv.x >> 16));
        float rz = bf2f((unsigned short)(rv.y & 0xffff)), rw = bf2f((unsigned short)(rv.y >> 16));
        float4 z;
        z.x = fmaxf(ax * w2 + b2, 0.f) + fmaxf(rx * wsc + bsc, 0.f);
        z.y = fmaxf(ay * w2 + b2, 0.f) + fmaxf(ry * wsc + bsc, 0.f);
        z.z = fmaxf(az * w2 + b2, 0.f) + fmaxf(rz * wsc + bsc, 0.f);
        z.w = fmaxf(aw * w2 + b2, 0.f) + fmaxf(rw * wsc + bsc, 0.f);
        o4[i] = z;
        s  += z.x + z.y + z.z + z.w;
        ss += z.x * z.x + z.y * z.y + z.z * z.z + z.w * z.w;
    }
    #pragma unroll
    for (int o = 32; o > 0; o >>= 1) { s += __shfl_down(s, o, 64); ss += __shfl_down(ss, o, 64); }
    __shared__ float red[4][2];
    int wid = threadIdx.x >> 6, lane = threadIdx.x & 63;
    if (lane == 0) { red[wid][0] = s; red[wid][1] = ss; }
    __syncthreads();
    if (threadIdx.x == 0) {
        float S  = red[0][0] + red[1][0] + red[2][0] + red[3][0];
        float SS = red[0][1] + red[1][1] + red[2][1] + red[3][1];
        atomicAdd(&st3[span * 2],     S);
        atomicAdd(&st3[span * 2 + 1], SS);
    }
}

// ---------------- final gn_out, span-based (hoisted params) ----------------
__global__ void norm_kernel(float* __restrict__ out, const float* __restrict__ st3,
                            const float* __restrict__ gw, const float* __restrict__ gb)
{
    const float invcnt = 1.0f / (128.0f * NPIX);
    int span = blockIdx.y;
    int cg = span & 3;
    float2 p = gn_params(st3, span, invcnt);
    size_t base = (size_t)span * (128 * (size_t)NPIX);
    float4* o4 = reinterpret_cast<float4*>(out + base);
    const size_t len4 = (128 * (size_t)NPIX) >> 2;
    for (size_t i = (size_t)blockIdx.x * blockDim.x + threadIdx.x; i < len4;
         i += (size_t)gridDim.x * blockDim.x) {
        int c = cg * 128 + (int)((i * 4) / NPIX);
        float w_ = gw[c] * p.y, b_ = gb[c] - p.x * p.y * gw[c];
        float4 a = o4[i], z;
        z.x = a.x * w_ + b_; z.y = a.y * w_ + b_; z.z = a.z * w_ + b_; z.w = a.w * w_ + b_;
        o4[i] = z;
    }
}

extern "C" void kernel_launch(void* const* d_in, const int* in_sizes, int n_in,
                              void* d_out, int out_size, void* d_ws, size_t ws_size,
                              hipStream_t stream) {
    (void)in_sizes; (void)n_in; (void)out_size; (void)ws_size;
    const float* corr     = (const float*)d_in[0];
    const int*   smask    = (const int*)  d_in[1];
    const float* W_sc     = (const float*)d_in[2];
    const float* gn_sc_w  = (const float*)d_in[3];
    const float* gn_sc_b  = (const float*)d_in[4];
    const float* W_qkv    = (const float*)d_in[5];
    const float* b_qkv    = (const float*)d_in[6];
    const float* gn1_w    = (const float*)d_in[7];
    const float* gn1_b    = (const float*)d_in[8];
    const float* W_agg    = (const float*)d_in[9];
    const float* gn2_w    = (const float*)d_in[10];
    const float* gn2_b    = (const float*)d_in[11];
    const float* gn_out_w = (const float*)d_in[12];
    const float* gn_out_b = (const float*)d_in[13];
    float* out = (float*)d_out;

    unsigned short* ws = (unsigned short*)d_ws;
    unsigned short* corrT  = ws;                           // 34,603,008 sh
    unsigned short* kbuf   = corrT  + (size_t)34603008;    // 69,206,016 sh region
    unsigned short* aggb   = kbuf;                         // 34,078,720 sh (bf16 agg out)
    unsigned short* scrb   = kbuf + (size_t)34078720;      // 34,078,720 sh (bf16 sc out)
    unsigned short* vbuf   = kbuf   + (size_t)69206016;    // (dead space, kept for layout)
    unsigned short* corrpT = vbuf   + (size_t)69206016;    //  8,519,680 sh
    unsigned short* qpT    = corrpT + (size_t)8519680;     // 17,039,360 sh
    unsigned short* attT   = qpT    + (size_t)17039360;    // 17,039,360 sh
    unsigned short* wbuf   = attT   + (size_t)17039360;    //    294,912 sh
    float* bias  = (float*)(wbuf + (size_t)294912);        // 1,088 f  ([b][272])
    float* stats = bias + 1088;                            // 128 f
    float* st_sc = stats, *st1 = stats + 32, *st2 = stats + 64, *st3 = stats + 96;
    (void)vbuf;

    const float inv1 = 1.0f / (64.0f * (float)NPIX);

    hipMemsetAsync(stats, 0, 128 * sizeof(float), stream);
    wprep_kernel<<<dim3(1152), dim3(256), 0, stream>>>(W_qkv, W_sc, W_agg, wbuf);
    mask_kernel<<<dim3(NB), dim3(320), 0, stream>>>(smask, bias);
    tpool_kernel<<<dim3(TQ, 2, NB), dim3(256), 0, stream>>>(corr, corrT, corrpT);
    // Q projection: qpT[b][n][256] = Wq x corrpT + bq
    mgemm_kernel<0,128><<<dim3(130, 2, NB), dim3(256), 0, stream>>>(
        corrpT, wbuf, NPIX, qpT, b_qkv,
        nullptr, nullptr, nullptr, 0.f, nullptr);
    // fused KV projection + attention + gn1 stats (XCD-local (g,q) remap inside)
    attn_kernel<<<dim3(8, TQ, NB), dim3(320), 0, stream>>>(
        corrT, wbuf + 32768, b_qkv + 256, qpT, bias, attT, st1);
    // agg conv (bf16 out) with fused gn1+relu on input and fused st2 accumulation
    mgemm_kernel<3,256><<<dim3(130, 4, NB), dim3(256), 0, stream>>>(
        attT, wbuf + 163840, NPIX, aggb, nullptr,
        st1, gn1_w, gn1_b, inv1, st2);
    // residual conv (bf16 out) with fused st_sc accumulation
    mgemm_kernel<2,128><<<dim3(130, 4, NB), dim3(256), 0, stream>>>(
        corrpT, wbuf + 98304, NPIX, scrb, nullptr,
        nullptr, nullptr, nullptr, 0.f, st_sc);
    // z + fused st3 accumulation (span-based, bf16 inputs)
    z_kernel<<<dim3(256, 16), dim3(256), 0, stream>>>(
        out, aggb, scrb, st2, st_sc, gn2_w, gn2_b, gn_sc_w, gn_sc_b, st3);
    norm_kernel<<<dim3(256, 16), dim3(256), 0, stream>>>(out, st3, gn_out_w, gn_out_b);
}